// Round 1
// baseline (338.168 us; speedup 1.0000x reference)
//
#include <hip/hip_runtime.h>

// Pipeline: prep_w -> qkv_gemm (fused Q,K,V; V stored transposed) -> attn (flash) -> out_gemm
// All compute in bf16 MFMA (16x16x32), f32 accumulate. Output f32.
// ws layout: [0,512KB) WtQ/K/V/O bf16 transposed; then q, k, Vt, attv (16MB each) from 1MB.

typedef __attribute__((ext_vector_type(4))) float  f32x4;
typedef __attribute__((ext_vector_type(8))) short  s16x8;
typedef __attribute__((ext_vector_type(4))) short  s16x4;

__device__ __forceinline__ short f2b(float f) {
    union { float f; unsigned u; } v; v.f = f;
    unsigned r = v.u + 0x7FFFu + ((v.u >> 16) & 1u);
    return (short)(r >> 16);
}

// ---- Wt[w][n][k] = (bf16) W_w[k][n], w order {q,k,v,o} ----
__global__ void prep_w(const float* __restrict__ Wq, const float* __restrict__ Wk,
                       const float* __restrict__ Wv, const float* __restrict__ Wo,
                       short* __restrict__ Wt) {
    int idx = blockIdx.x * 256 + threadIdx.x;       // 4 * 65536 total
    int w = idx >> 16, rem = idx & 65535;
    int n = rem >> 8, kk = rem & 255;
    const float* W = (w == 0) ? Wq : (w == 1) ? Wk : (w == 2) ? Wv : Wo;
    Wt[idx] = f2b(W[kk * 256 + n]);
}

// ---- fused QKV projection: x[32768,256] f32 @ W^T -> relu -> bf16 ----
// q,k stored [seq][h]; v stored transposed Vt[b][h][seq].
__global__ __launch_bounds__(256) void qkv_gemm(
        const float* __restrict__ x, const short* __restrict__ Wt,
        const float* __restrict__ bq, const float* __restrict__ bk, const float* __restrict__ bv,
        short* __restrict__ qO, short* __restrict__ kO, short* __restrict__ vtO) {
    __shared__ short a_lds[128][72];        // x tile bf16 (also reused as epilogue bounce)
    __shared__ short b_lds[3][64][72];      // W^T tiles
    const int tid = threadIdx.x;
    const int bm = blockIdx.x >> 2, bn = blockIdx.x & 3;
    const int s0 = bm * 128, n0 = bn * 64;
    const int wid = tid >> 6, l = tid & 63, lo4 = l & 15, hi4 = l >> 4;
    const int wm = wid >> 1, wn = wid & 1;

    f32x4 acc[3][4][2];
    #pragma unroll
    for (int w = 0; w < 3; ++w)
        #pragma unroll
        for (int mi = 0; mi < 4; ++mi)
            #pragma unroll
            for (int ni = 0; ni < 2; ++ni)
                acc[w][mi][ni] = (f32x4){0.f, 0.f, 0.f, 0.f};

    for (int kt = 0; kt < 4; ++kt) {
        const int k0 = kt * 64;
        #pragma unroll
        for (int i = 0; i < 8; ++i) {                       // stage A: 128x64 f32 -> bf16
            int ch = i * 256 + tid;
            int row = ch >> 4, c4 = (ch & 15) * 4;
            f32x4 xv = *(const f32x4*)(x + (size_t)(s0 + row) * 256 + k0 + c4);
            s16x4 pk = { f2b(xv.x), f2b(xv.y), f2b(xv.z), f2b(xv.w) };
            *(s16x4*)&a_lds[row][c4] = pk;
        }
        #pragma unroll
        for (int w = 0; w < 3; ++w) {                       // stage B: 3 x 64x64 bf16
            #pragma unroll
            for (int i = 0; i < 2; ++i) {
                int ch = i * 256 + tid;
                int n = ch >> 3, c8 = (ch & 7) * 8;
                *(s16x8*)&b_lds[w][n][c8] =
                    *(const s16x8*)(Wt + (size_t)w * 65536 + (size_t)(n0 + n) * 256 + k0 + c8);
            }
        }
        __syncthreads();
        s16x8 af[4][2];
        #pragma unroll
        for (int mi = 0; mi < 4; ++mi)
            #pragma unroll
            for (int kk = 0; kk < 2; ++kk)
                af[mi][kk] = *(s16x8*)&a_lds[wm * 64 + mi * 16 + lo4][kk * 32 + hi4 * 8];
        #pragma unroll
        for (int w = 0; w < 3; ++w)
            #pragma unroll
            for (int ni = 0; ni < 2; ++ni)
                #pragma unroll
                for (int kk = 0; kk < 2; ++kk) {
                    s16x8 bfr = *(s16x8*)&b_lds[w][wn * 32 + ni * 16 + lo4][kk * 32 + hi4 * 8];
                    #pragma unroll
                    for (int mi = 0; mi < 4; ++mi)
                        acc[w][mi][ni] = __builtin_amdgcn_mfma_f32_16x16x32_bf16(
                            af[mi][kk], bfr, acc[w][mi][ni], 0, 0, 0);
                }
        __syncthreads();
    }

    const float* bias[3] = { bq, bk, bv };
    for (int w = 0; w < 3; ++w) {
        #pragma unroll
        for (int mi = 0; mi < 4; ++mi)
            #pragma unroll
            for (int ni = 0; ni < 2; ++ni)
                #pragma unroll
                for (int j = 0; j < 4; ++j) {
                    int r = wm * 64 + mi * 16 + hi4 * 4 + j;
                    int c = wn * 32 + ni * 16 + lo4;
                    float v = acc[w][mi][ni][j] + bias[w][n0 + c];
                    a_lds[r][c] = f2b(fmaxf(v, 0.f));
                }
        __syncthreads();
        if (w < 2) {
            short* outp = (w == 0) ? qO : kO;
            #pragma unroll
            for (int i = 0; i < 4; ++i) {
                int ch = i * 256 + tid;
                int row = ch >> 3, c8 = (ch & 7) * 8;
                *(s16x8*)(outp + (size_t)(s0 + row) * 256 + n0 + c8) = *(s16x8*)&a_lds[row][c8];
            }
        } else {
            int bb = s0 >> 10, nn = s0 & 1023;              // block spans a single batch
            #pragma unroll
            for (int i = 0; i < 4; ++i) {
                int ch = i * 256 + tid;
                int h = ch >> 4, sc = (ch & 15) * 8;
                s16x8 t;
                #pragma unroll
                for (int e = 0; e < 8; ++e) t[e] = a_lds[sc + e][h];
                *(s16x8*)(vtO + ((size_t)bb * 256 + n0 + h) * 1024 + nn + sc) = t;
            }
        }
        __syncthreads();
    }
}

// ---- flash attention: 4 independent waves/block, 16 q-rows each ----
__global__ __launch_bounds__(256) void attn(
        const short* __restrict__ q, const short* __restrict__ k,
        const short* __restrict__ vt, const float* __restrict__ mask,
        short* __restrict__ attv) {
    __shared__ short p_lds[4][16][72];      // per-wave P relayout buffer
    __shared__ short o_lds[4][16][264];     // per-wave epilogue bounce
    const int tid = threadIdx.x, wid = tid >> 6, l = tid & 63;
    const int lo4 = l & 15, hi4 = l >> 4;
    const int b = blockIdx.x >> 4, qb = blockIdx.x & 15;
    const int q0 = qb * 64 + wid * 16;

    s16x8 qf[8];
    {
        const short* qp = q + ((size_t)b * 1024 + q0 + lo4) * 256 + hi4 * 8;
        #pragma unroll
        for (int t = 0; t < 8; ++t) qf[t] = *(const s16x8*)(qp + t * 32);
    }
    f32x4 oacc[16];
    #pragma unroll
    for (int t = 0; t < 16; ++t) oacc[t] = (f32x4){0.f, 0.f, 0.f, 0.f};
    float m_run[4] = { -1e30f, -1e30f, -1e30f, -1e30f };
    float l_run[4] = { 0.f, 0.f, 0.f, 0.f };
    const size_t mbase = (size_t)b * 1024 * 1024;

    for (int kt = 0; kt < 16; ++kt) {
        const int c0 = kt * 64;
        f32x4 s[4];
        #pragma unroll
        for (int ct = 0; ct < 4; ++ct) s[ct] = (f32x4){0.f, 0.f, 0.f, 0.f};
        const short* kp = k + ((size_t)b * 1024 + c0 + lo4) * 256 + hi4 * 8;
        #pragma unroll
        for (int ct = 0; ct < 4; ++ct)
            #pragma unroll
            for (int t = 0; t < 8; ++t) {
                s16x8 kf = *(const s16x8*)(kp + (size_t)ct * 16 * 256 + t * 32);
                s[ct] = __builtin_amdgcn_mfma_f32_16x16x32_bf16(qf[t], kf, s[ct], 0, 0, 0);
            }
        // mask + online softmax (rows r = hi4*4+j live in 16-lane groups)
        float sm[4][4];
        #pragma unroll
        for (int j = 0; j < 4; ++j) {
            const float* mrow = mask + mbase + (size_t)(q0 + hi4 * 4 + j) * 1024 + c0 + lo4;
            #pragma unroll
            for (int ct = 0; ct < 4; ++ct) {
                float mv = mrow[ct * 16];
                sm[ct][j] = (mv != 0.f) ? s[ct][j] : -1e30f;
            }
        }
        float scale[4], p[4][4];
        #pragma unroll
        for (int j = 0; j < 4; ++j) {
            float t = fmaxf(fmaxf(sm[0][j], sm[1][j]), fmaxf(sm[2][j], sm[3][j]));
            t = fmaxf(t, __shfl_xor(t, 1));
            t = fmaxf(t, __shfl_xor(t, 2));
            t = fmaxf(t, __shfl_xor(t, 4));
            t = fmaxf(t, __shfl_xor(t, 8));
            float mnew = fmaxf(m_run[j], t);
            scale[j] = __expf(m_run[j] - mnew);
            m_run[j] = mnew;
            float su = 0.f;
            #pragma unroll
            for (int ct = 0; ct < 4; ++ct) { p[ct][j] = __expf(sm[ct][j] - mnew); su += p[ct][j]; }
            su += __shfl_xor(su, 1);
            su += __shfl_xor(su, 2);
            su += __shfl_xor(su, 4);
            su += __shfl_xor(su, 8);
            l_run[j] = l_run[j] * scale[j] + su;
        }
        #pragma unroll
        for (int t = 0; t < 16; ++t)
            #pragma unroll
            for (int j = 0; j < 4; ++j) oacc[t][j] *= scale[j];
        // P (D-layout) -> LDS -> A-fragment layout
        #pragma unroll
        for (int ct = 0; ct < 4; ++ct)
            #pragma unroll
            for (int j = 0; j < 4; ++j)
                p_lds[wid][hi4 * 4 + j][ct * 16 + lo4] = f2b(p[ct][j]);
        asm volatile("s_waitcnt lgkmcnt(0)" ::: "memory");
        s16x8 pa0 = *(s16x8*)&p_lds[wid][lo4][hi4 * 8];
        s16x8 pa1 = *(s16x8*)&p_lds[wid][lo4][32 + hi4 * 8];
        const short* vp = vt + ((size_t)b * 256 + lo4) * 1024 + c0 + hi4 * 8;
        #pragma unroll
        for (int nt = 0; nt < 16; ++nt) {
            s16x8 vf0 = *(const s16x8*)(vp + (size_t)nt * 16 * 1024);
            s16x8 vf1 = *(const s16x8*)(vp + (size_t)nt * 16 * 1024 + 32);
            oacc[nt] = __builtin_amdgcn_mfma_f32_16x16x32_bf16(pa0, vf0, oacc[nt], 0, 0, 0);
            oacc[nt] = __builtin_amdgcn_mfma_f32_16x16x32_bf16(pa1, vf1, oacc[nt], 0, 0, 0);
        }
    }
    float inv[4];
    #pragma unroll
    for (int j = 0; j < 4; ++j) inv[j] = 1.f / l_run[j];
    #pragma unroll
    for (int nt = 0; nt < 16; ++nt)
        #pragma unroll
        for (int j = 0; j < 4; ++j)
            o_lds[wid][hi4 * 4 + j][nt * 16 + lo4] = f2b(oacc[nt][j] * inv[j]);
    asm volatile("s_waitcnt lgkmcnt(0)" ::: "memory");
    #pragma unroll
    for (int c = 0; c < 8; ++c) {
        int idx = c * 64 + l;
        int row = idx >> 5, c8 = (idx & 31) * 8;
        *(s16x8*)(attv + ((size_t)b * 1024 + q0 + row) * 256 + c8) = *(s16x8*)&o_lds[wid][row][c8];
    }
}

// ---- output GEMM: attv bf16 @ Wo^T + bo -> relu -> f32 ----
__global__ __launch_bounds__(256) void out_gemm(
        const short* __restrict__ a, const short* __restrict__ Wto,
        const float* __restrict__ bo, float* __restrict__ out) {
    __shared__ short a_lds[128][72];
    __shared__ short b_lds[64][72];
    __shared__ float bounce[128][68];
    const int tid = threadIdx.x;
    const int bm = blockIdx.x >> 2, bn = blockIdx.x & 3;
    const int s0 = bm * 128, n0 = bn * 64;
    const int wid = tid >> 6, l = tid & 63, lo4 = l & 15, hi4 = l >> 4;
    const int wm = wid >> 1, wn = wid & 1;
    f32x4 acc[4][2];
    #pragma unroll
    for (int mi = 0; mi < 4; ++mi)
        #pragma unroll
        for (int ni = 0; ni < 2; ++ni) acc[mi][ni] = (f32x4){0.f, 0.f, 0.f, 0.f};

    for (int kt = 0; kt < 4; ++kt) {
        const int k0 = kt * 64;
        #pragma unroll
        for (int i = 0; i < 4; ++i) {
            int ch = i * 256 + tid;
            int row = ch >> 3, c8 = (ch & 7) * 8;
            *(s16x8*)&a_lds[row][c8] = *(const s16x8*)(a + (size_t)(s0 + row) * 256 + k0 + c8);
        }
        #pragma unroll
        for (int i = 0; i < 2; ++i) {
            int ch = i * 256 + tid;
            int n = ch >> 3, c8 = (ch & 7) * 8;
            *(s16x8*)&b_lds[n][c8] = *(const s16x8*)(Wto + (size_t)(n0 + n) * 256 + k0 + c8);
        }
        __syncthreads();
        s16x8 af[4][2];
        #pragma unroll
        for (int mi = 0; mi < 4; ++mi)
            #pragma unroll
            for (int kk = 0; kk < 2; ++kk)
                af[mi][kk] = *(s16x8*)&a_lds[wm * 64 + mi * 16 + lo4][kk * 32 + hi4 * 8];
        #pragma unroll
        for (int ni = 0; ni < 2; ++ni)
            #pragma unroll
            for (int kk = 0; kk < 2; ++kk) {
                s16x8 bfr = *(s16x8*)&b_lds[wn * 32 + ni * 16 + lo4][kk * 32 + hi4 * 8];
                #pragma unroll
                for (int mi = 0; mi < 4; ++mi)
                    acc[mi][ni] = __builtin_amdgcn_mfma_f32_16x16x32_bf16(
                        af[mi][kk], bfr, acc[mi][ni], 0, 0, 0);
            }
        __syncthreads();
    }
    #pragma unroll
    for (int mi = 0; mi < 4; ++mi)
        #pragma unroll
        for (int ni = 0; ni < 2; ++ni)
            #pragma unroll
            for (int j = 0; j < 4; ++j) {
                int r = wm * 64 + mi * 16 + hi4 * 4 + j;
                int c = wn * 32 + ni * 16 + lo4;
                bounce[r][c] = fmaxf(acc[mi][ni][j] + bo[n0 + c], 0.f);
            }
    __syncthreads();
    #pragma unroll
    for (int i = 0; i < 8; ++i) {
        int ch = i * 256 + tid;
        int row = ch >> 4, c4 = (ch & 15) * 4;
        *(f32x4*)(out + (size_t)(s0 + row) * 256 + n0 + c4) = *(f32x4*)&bounce[row][c4];
    }
}

extern "C" void kernel_launch(void* const* d_in, const int* in_sizes, int n_in,
                              void* d_out, int out_size, void* d_ws, size_t ws_size,
                              hipStream_t stream) {
    const float* x    = (const float*)d_in[0];
    const float* mask = (const float*)d_in[1];
    const float* Wv   = (const float*)d_in[2];
    const float* bv   = (const float*)d_in[3];
    const float* Wk   = (const float*)d_in[4];
    const float* bk   = (const float*)d_in[5];
    const float* Wq   = (const float*)d_in[6];
    const float* bq   = (const float*)d_in[7];
    const float* Wo   = (const float*)d_in[8];
    const float* bo   = (const float*)d_in[9];
    float* out = (float*)d_out;

    short* Wt  = (short*)d_ws;                              // 4*65536 bf16 = 512 KB
    short* qB  = (short*)((char*)d_ws + (1 << 20));         // 16 MB each below
    short* kB  = qB  + (size_t)32768 * 256;
    short* vtB = kB  + (size_t)32768 * 256;
    short* avB = vtB + (size_t)32768 * 256;
    (void)in_sizes; (void)n_in; (void)out_size; (void)ws_size;

    prep_w<<<1024, 256, 0, stream>>>(Wq, Wk, Wv, Wo, Wt);
    qkv_gemm<<<1024, 256, 0, stream>>>(x, Wt, bq, bk, bv, qB, kB, vtB);
    attn<<<512, 256, 0, stream>>>(qB, kB, vtB, mask, avB);
    out_gemm<<<1024, 256, 0, stream>>>(avB, Wt + 3 * 65536, bo, out);
}

// Round 2
// 160.993 us; speedup vs baseline: 2.1005x; 2.1005x over previous
//
#include <hip/hip_runtime.h>

// Pipeline: prep_w -> mask_pack -> qkv_gemm (fused Q,K,V; K & V^T written XOR-swizzled)
//           -> attn (flash, LDS-staged K/V via global_load_lds, bit mask) -> out_gemm
// All matmul compute in bf16 MFMA (16x16x32), f32 accumulate. Output f32.

typedef __attribute__((ext_vector_type(4))) float  f32x4;
typedef __attribute__((ext_vector_type(8))) short  s16x8;
typedef __attribute__((ext_vector_type(4))) short  s16x4;

__device__ __forceinline__ short f2b(float f) {
    union { float f; unsigned u; } v; v.f = f;
    unsigned r = v.u + 0x7FFFu + ((v.u >> 16) & 1u);
    return (short)(r >> 16);
}

__device__ __forceinline__ void gl_lds16(const short* g, short* l) {
    __builtin_amdgcn_global_load_lds(
        (const __attribute__((address_space(1))) unsigned int*)g,
        (__attribute__((address_space(3))) unsigned int*)l, 16, 0, 0);
}

// ---- Wt[w][n][k] = (bf16) W_w[k][n], w order {q,k,v,o} ----
__global__ void prep_w(const float* __restrict__ Wq, const float* __restrict__ Wk,
                       const float* __restrict__ Wv, const float* __restrict__ Wo,
                       short* __restrict__ Wt) {
    int idx = blockIdx.x * 256 + threadIdx.x;       // 4 * 65536 total
    int w = idx >> 16, rem = idx & 65535;
    int n = rem >> 8, kk = rem & 255;
    const float* W = (w == 0) ? Wq : (w == 1) ? Wk : (w == 2) ? Wv : Wo;
    Wt[idx] = f2b(W[kk * 256 + n]);
}

// ---- mask bit-pack: mp[i] bit e = (mask[i*32+e] != 0) ----
__global__ __launch_bounds__(256) void mask_pack(const float* __restrict__ m,
                                                 unsigned* __restrict__ mp) {
    int gid = blockIdx.x * 256 + threadIdx.x;       // 1,048,576 threads
    const float* p = m + (size_t)gid * 32;
    unsigned b = 0;
    #pragma unroll
    for (int i = 0; i < 8; ++i) {
        f32x4 v = *(const f32x4*)(p + i * 4);
        b |= (unsigned)(v.x != 0.f) << (i * 4);
        b |= (unsigned)(v.y != 0.f) << (i * 4 + 1);
        b |= (unsigned)(v.z != 0.f) << (i * 4 + 2);
        b |= (unsigned)(v.w != 0.f) << (i * 4 + 3);
    }
    mp[gid] = b;
}

// ---- fused QKV projection: x[32768,256] f32 @ W^T -> relu -> bf16 ----
// q stored [seq][h] linear; k stored [seq][h] with 16B-chunk low3 XOR (seq&7);
// v stored transposed Vt[b][h][seq] with 16B-chunk low3 XOR (h&7).
__global__ __launch_bounds__(256) void qkv_gemm(
        const float* __restrict__ x, const short* __restrict__ Wt,
        const float* __restrict__ bq, const float* __restrict__ bk, const float* __restrict__ bv,
        short* __restrict__ qO, short* __restrict__ kO, short* __restrict__ vtO) {
    __shared__ short a_lds[128][72];        // x tile bf16 (also reused as epilogue bounce)
    __shared__ short b_lds[3][64][72];      // W^T tiles
    const int tid = threadIdx.x;
    const int bm = blockIdx.x >> 2, bn = blockIdx.x & 3;
    const int s0 = bm * 128, n0 = bn * 64;
    const int wid = tid >> 6, l = tid & 63, lo4 = l & 15, hi4 = l >> 4;
    const int wm = wid >> 1, wn = wid & 1;

    f32x4 acc[3][4][2];
    #pragma unroll
    for (int w = 0; w < 3; ++w)
        #pragma unroll
        for (int mi = 0; mi < 4; ++mi)
            #pragma unroll
            for (int ni = 0; ni < 2; ++ni)
                acc[w][mi][ni] = (f32x4){0.f, 0.f, 0.f, 0.f};

    for (int kt = 0; kt < 4; ++kt) {
        const int k0 = kt * 64;
        #pragma unroll
        for (int i = 0; i < 8; ++i) {                       // stage A: 128x64 f32 -> bf16
            int ch = i * 256 + tid;
            int row = ch >> 4, c4 = (ch & 15) * 4;
            f32x4 xv = *(const f32x4*)(x + (size_t)(s0 + row) * 256 + k0 + c4);
            s16x4 pk = { f2b(xv.x), f2b(xv.y), f2b(xv.z), f2b(xv.w) };
            *(s16x4*)&a_lds[row][c4] = pk;
        }
        #pragma unroll
        for (int w = 0; w < 3; ++w) {                       // stage B: 3 x 64x64 bf16
            #pragma unroll
            for (int i = 0; i < 2; ++i) {
                int ch = i * 256 + tid;
                int n = ch >> 3, c8 = (ch & 7) * 8;
                *(s16x8*)&b_lds[w][n][c8] =
                    *(const s16x8*)(Wt + (size_t)w * 65536 + (size_t)(n0 + n) * 256 + k0 + c8);
            }
        }
        __syncthreads();
        s16x8 af[4][2];
        #pragma unroll
        for (int mi = 0; mi < 4; ++mi)
            #pragma unroll
            for (int kk = 0; kk < 2; ++kk)
                af[mi][kk] = *(s16x8*)&a_lds[wm * 64 + mi * 16 + lo4][kk * 32 + hi4 * 8];
        #pragma unroll
        for (int w = 0; w < 3; ++w)
            #pragma unroll
            for (int ni = 0; ni < 2; ++ni)
                #pragma unroll
                for (int kk = 0; kk < 2; ++kk) {
                    s16x8 bfr = *(s16x8*)&b_lds[w][wn * 32 + ni * 16 + lo4][kk * 32 + hi4 * 8];
                    #pragma unroll
                    for (int mi = 0; mi < 4; ++mi)
                        acc[w][mi][ni] = __builtin_amdgcn_mfma_f32_16x16x32_bf16(
                            af[mi][kk], bfr, acc[w][mi][ni], 0, 0, 0);
                }
        __syncthreads();
    }

    const float* bias[3] = { bq, bk, bv };
    for (int w = 0; w < 3; ++w) {
        #pragma unroll
        for (int mi = 0; mi < 4; ++mi)
            #pragma unroll
            for (int ni = 0; ni < 2; ++ni)
                #pragma unroll
                for (int j = 0; j < 4; ++j) {
                    int r = wm * 64 + mi * 16 + hi4 * 4 + j;
                    int c = wn * 32 + ni * 16 + lo4;
                    float v = acc[w][mi][ni][j] + bias[w][n0 + c];
                    a_lds[r][c] = f2b(fmaxf(v, 0.f));
                }
        __syncthreads();
        if (w == 0) {
            #pragma unroll
            for (int i = 0; i < 4; ++i) {
                int ch = i * 256 + tid;
                int row = ch >> 3, c8 = (ch & 7) * 8;
                *(s16x8*)(qO + (size_t)(s0 + row) * 256 + n0 + c8) = *(s16x8*)&a_lds[row][c8];
            }
        } else if (w == 1) {
            #pragma unroll
            for (int i = 0; i < 4; ++i) {
                int ch = i * 256 + tid;
                int row = ch >> 3, c8 = (ch & 7) * 8;
                int swz = ((c8 >> 3) ^ (row & 7)) * 8;      // seq-keyed chunk XOR
                *(s16x8*)(kO + (size_t)(s0 + row) * 256 + n0 + swz) = *(s16x8*)&a_lds[row][c8];
            }
        } else {
            int bb = s0 >> 10, nn = s0 & 1023;              // block spans a single batch
            #pragma unroll
            for (int i = 0; i < 4; ++i) {
                int ch = i * 256 + tid;
                int h = ch >> 4, sc = (ch & 15) * 8;
                s16x8 t;
                #pragma unroll
                for (int e = 0; e < 8; ++e) t[e] = a_lds[sc + e][h];
                int cil = sc >> 3;                          // 0..15
                int swz = (cil & 8) | ((cil & 7) ^ ((n0 + h) & 7));   // h-keyed chunk XOR
                *(s16x8*)(vtO + ((size_t)bb * 256 + n0 + h) * 1024 + nn + swz * 8) = t;
            }
        }
        __syncthreads();
    }
}

// ---- flash attention: 8 waves/block, Q-tile 128 (16 rows/wave), K/V LDS-staged ----
__global__ __launch_bounds__(512) void attn(
        const short* __restrict__ q, const short* __restrict__ k,
        const short* __restrict__ vt, const unsigned* __restrict__ mp,
        short* __restrict__ attv) {
    __shared__ short kv[16384];             // 32KB: K[64][256] phase A, V[256][64] phase B
    __shared__ short p_lds[8][16][72];      // per-wave P relayout / epilogue bounce
    const int tid = threadIdx.x, wid = tid >> 6, l = tid & 63;
    const int lo4 = l & 15, hi4 = l >> 4;
    const int bid = blockIdx.x;
    const int swz = (bid & 7) * 32 + (bid >> 3);    // XCD-chunked: 4 batches per XCD
    const int b = swz >> 3, qb = swz & 7;
    const int q0 = qb * 128 + wid * 16;
    const size_t bq_row = (size_t)b * 1024 + q0;

    s16x8 qf[8];
    {
        const short* qp = q + (bq_row + lo4) * 256 + hi4 * 8;
        #pragma unroll
        for (int t = 0; t < 8; ++t) qf[t] = *(const s16x8*)(qp + t * 32);
    }
    f32x4 oacc[16];
    #pragma unroll
    for (int t = 0; t < 16; ++t) oacc[t] = (f32x4){0.f, 0.f, 0.f, 0.f};
    float m_run[4] = { -1e30f, -1e30f, -1e30f, -1e30f };
    float l_run[4] = { 0.f, 0.f, 0.f, 0.f };

    const short* kb  = k  + (size_t)b * 1024 * 256;
    const short* vtg = vt + (size_t)b * 256 * 1024;
    const unsigned* mpb = mp + ((size_t)b << 15);

    for (int kt = 0; kt < 16; ++kt) {
        const int c0 = kt * 64;
        // ---- stage K tile [64][256] (global layout already row-XOR-swizzled) ----
        __syncthreads();                                    // prior V reads complete
        {
            const short* ktg = kb + (size_t)c0 * 256;       // 32KB contiguous
            #pragma unroll
            for (int i = 0; i < 4; ++i) {
                int cbase = i * 512 + wid * 64;             // wave-uniform chunk base
                gl_lds16(ktg + (size_t)(cbase + l) * 8, &kv[(size_t)cbase * 8]);
            }
        }
        asm volatile("s_waitcnt vmcnt(0)" ::: "memory");
        __syncthreads();
        // ---- QK^T ----
        f32x4 s[4];
        #pragma unroll
        for (int ct = 0; ct < 4; ++ct) s[ct] = (f32x4){0.f, 0.f, 0.f, 0.f};
        #pragma unroll
        for (int ct = 0; ct < 4; ++ct) {
            int row = ct * 16 + lo4, rx = row & 7;
            #pragma unroll
            for (int t = 0; t < 8; ++t) {
                int ch = t * 4 + hi4;
                int sc = (ch & 24) | ((ch & 7) ^ rx);
                s16x8 kf = *(s16x8*)&kv[row * 256 + sc * 8];
                s[ct] = __builtin_amdgcn_mfma_f32_16x16x32_bf16(qf[t], kf, s[ct], 0, 0, 0);
            }
        }
        // ---- masked online softmax (bit mask, broadcast u32 loads) ----
        float sm[4][4];
        #pragma unroll
        for (int j = 0; j < 4; ++j) {
            size_t widx = (size_t)(q0 + hi4 * 4 + j) * 32 + (c0 >> 5);
            unsigned w0 = mpb[widx], w1 = mpb[widx + 1];
            sm[0][j] = ((w0 >> lo4) & 1)        ? s[0][j] : -1e30f;
            sm[1][j] = ((w0 >> (16 + lo4)) & 1) ? s[1][j] : -1e30f;
            sm[2][j] = ((w1 >> lo4) & 1)        ? s[2][j] : -1e30f;
            sm[3][j] = ((w1 >> (16 + lo4)) & 1) ? s[3][j] : -1e30f;
        }
        float scale[4], p[4][4];
        #pragma unroll
        for (int j = 0; j < 4; ++j) {
            float t = fmaxf(fmaxf(sm[0][j], sm[1][j]), fmaxf(sm[2][j], sm[3][j]));
            t = fmaxf(t, __shfl_xor(t, 1));
            t = fmaxf(t, __shfl_xor(t, 2));
            t = fmaxf(t, __shfl_xor(t, 4));
            t = fmaxf(t, __shfl_xor(t, 8));
            float mnew = fmaxf(m_run[j], t);
            scale[j] = __expf(m_run[j] - mnew);
            m_run[j] = mnew;
            float su = 0.f;
            #pragma unroll
            for (int ct = 0; ct < 4; ++ct) { p[ct][j] = __expf(sm[ct][j] - mnew); su += p[ct][j]; }
            su += __shfl_xor(su, 1);
            su += __shfl_xor(su, 2);
            su += __shfl_xor(su, 4);
            su += __shfl_xor(su, 8);
            l_run[j] = l_run[j] * scale[j] + su;
        }
        #pragma unroll
        for (int t = 0; t < 16; ++t)
            #pragma unroll
            for (int j = 0; j < 4; ++j) oacc[t][j] *= scale[j];
        // ---- P (D-layout) -> per-wave LDS -> A-fragment ----
        #pragma unroll
        for (int ct = 0; ct < 4; ++ct)
            #pragma unroll
            for (int j = 0; j < 4; ++j)
                p_lds[wid][hi4 * 4 + j][ct * 16 + lo4] = f2b(p[ct][j]);
        asm volatile("s_waitcnt lgkmcnt(0)" ::: "memory");
        s16x8 pa0 = *(s16x8*)&p_lds[wid][lo4][hi4 * 8];
        s16x8 pa1 = *(s16x8*)&p_lds[wid][lo4][32 + hi4 * 8];
        __syncthreads();                                    // all waves done reading K tile
        // ---- stage V tile [256][64] (global layout already h-XOR-swizzled) ----
        {
            #pragma unroll
            for (int i = 0; i < 4; ++i) {
                int cbase = i * 512 + wid * 64;             // wave-uniform chunk base
                int chunk = cbase + l;
                int h = chunk >> 3, cc = chunk & 7;
                gl_lds16(vtg + (size_t)h * 1024 + c0 + cc * 8, &kv[(size_t)cbase * 8]);
            }
        }
        asm volatile("s_waitcnt vmcnt(0)" ::: "memory");
        __syncthreads();
        // ---- PV ----
        #pragma unroll
        for (int nt = 0; nt < 16; ++nt) {
            int h = nt * 16 + lo4, hx = h & 7;
            s16x8 vf0 = *(s16x8*)&kv[h * 64 + (hi4 ^ hx) * 8];
            s16x8 vf1 = *(s16x8*)&kv[h * 64 + ((hi4 + 4) ^ hx) * 8];
            oacc[nt] = __builtin_amdgcn_mfma_f32_16x16x32_bf16(pa0, vf0, oacc[nt], 0, 0, 0);
            oacc[nt] = __builtin_amdgcn_mfma_f32_16x16x32_bf16(pa1, vf1, oacc[nt], 0, 0, 0);
        }
    }
    // ---- epilogue: normalize, bf16, coalesced store via per-wave LDS (4 passes) ----
    float inv[4];
    #pragma unroll
    for (int j = 0; j < 4; ++j) inv[j] = 1.f / l_run[j];
    #pragma unroll
    for (int g = 0; g < 4; ++g) {
        asm volatile("s_waitcnt lgkmcnt(0)" ::: "memory");  // prior pass reads done
        #pragma unroll
        for (int ntl = 0; ntl < 4; ++ntl)
            #pragma unroll
            for (int j = 0; j < 4; ++j)
                p_lds[wid][hi4 * 4 + j][ntl * 16 + lo4] = f2b(oacc[g * 4 + ntl][j] * inv[j]);
        asm volatile("s_waitcnt lgkmcnt(0)" ::: "memory");
        s16x8 r0 = *(s16x8*)&p_lds[wid][lo4][hi4 * 16];
        s16x8 r1 = *(s16x8*)&p_lds[wid][lo4][hi4 * 16 + 8];
        short* op = attv + (bq_row + lo4) * 256 + g * 64 + hi4 * 16;
        *(s16x8*)op = r0;
        *(s16x8*)(op + 8) = r1;
    }
}

// ---- output GEMM: attv bf16 @ Wo^T + bo -> relu -> f32 ----
__global__ __launch_bounds__(256) void out_gemm(
        const short* __restrict__ a, const short* __restrict__ Wto,
        const float* __restrict__ bo, float* __restrict__ out) {
    __shared__ short a_lds[128][72];
    __shared__ short b_lds[64][72];
    __shared__ float bounce[128][68];
    const int tid = threadIdx.x;
    const int bm = blockIdx.x >> 2, bn = blockIdx.x & 3;
    const int s0 = bm * 128, n0 = bn * 64;
    const int wid = tid >> 6, l = tid & 63, lo4 = l & 15, hi4 = l >> 4;
    const int wm = wid >> 1, wn = wid & 1;
    f32x4 acc[4][2];
    #pragma unroll
    for (int mi = 0; mi < 4; ++mi)
        #pragma unroll
        for (int ni = 0; ni < 2; ++ni) acc[mi][ni] = (f32x4){0.f, 0.f, 0.f, 0.f};

    for (int kt = 0; kt < 4; ++kt) {
        const int k0 = kt * 64;
        #pragma unroll
        for (int i = 0; i < 4; ++i) {
            int ch = i * 256 + tid;
            int row = ch >> 3, c8 = (ch & 7) * 8;
            *(s16x8*)&a_lds[row][c8] = *(const s16x8*)(a + (size_t)(s0 + row) * 256 + k0 + c8);
        }
        #pragma unroll
        for (int i = 0; i < 2; ++i) {
            int ch = i * 256 + tid;
            int n = ch >> 3, c8 = (ch & 7) * 8;
            *(s16x8*)&b_lds[n][c8] = *(const s16x8*)(Wto + (size_t)(n0 + n) * 256 + k0 + c8);
        }
        __syncthreads();
        s16x8 af[4][2];
        #pragma unroll
        for (int mi = 0; mi < 4; ++mi)
            #pragma unroll
            for (int kk = 0; kk < 2; ++kk)
                af[mi][kk] = *(s16x8*)&a_lds[wm * 64 + mi * 16 + lo4][kk * 32 + hi4 * 8];
        #pragma unroll
        for (int ni = 0; ni < 2; ++ni)
            #pragma unroll
            for (int kk = 0; kk < 2; ++kk) {
                s16x8 bfr = *(s16x8*)&b_lds[wn * 32 + ni * 16 + lo4][kk * 32 + hi4 * 8];
                #pragma unroll
                for (int mi = 0; mi < 4; ++mi)
                    acc[mi][ni] = __builtin_amdgcn_mfma_f32_16x16x32_bf16(
                        af[mi][kk], bfr, acc[mi][ni], 0, 0, 0);
            }
        __syncthreads();
    }
    #pragma unroll
    for (int mi = 0; mi < 4; ++mi)
        #pragma unroll
        for (int ni = 0; ni < 2; ++ni)
            #pragma unroll
            for (int j = 0; j < 4; ++j) {
                int r = wm * 64 + mi * 16 + hi4 * 4 + j;
                int c = wn * 32 + ni * 16 + lo4;
                bounce[r][c] = fmaxf(acc[mi][ni][j] + bo[n0 + c], 0.f);
            }
    __syncthreads();
    #pragma unroll
    for (int i = 0; i < 8; ++i) {
        int ch = i * 256 + tid;
        int row = ch >> 4, c4 = (ch & 15) * 4;
        *(f32x4*)(out + (size_t)(s0 + row) * 256 + n0 + c4) = *(f32x4*)&bounce[row][c4];
    }
}

extern "C" void kernel_launch(void* const* d_in, const int* in_sizes, int n_in,
                              void* d_out, int out_size, void* d_ws, size_t ws_size,
                              hipStream_t stream) {
    const float* x    = (const float*)d_in[0];
    const float* mask = (const float*)d_in[1];
    const float* Wv   = (const float*)d_in[2];
    const float* bv   = (const float*)d_in[3];
    const float* Wk   = (const float*)d_in[4];
    const float* bk   = (const float*)d_in[5];
    const float* Wq   = (const float*)d_in[6];
    const float* bq   = (const float*)d_in[7];
    const float* Wo   = (const float*)d_in[8];
    const float* bo   = (const float*)d_in[9];
    float* out = (float*)d_out;

    char* ws = (char*)d_ws;
    short*    Wt  = (short*)ws;                               // 512 KB @ 0
    unsigned* mpW = (unsigned*)(ws + (512 << 10));            // 4 MB  @ 0.5 MB
    short*    qB  = (short*)(ws + (4608 << 10));              // 16 MB @ 4.5 MB
    short*    kB  = qB  + (size_t)32768 * 256;                // @ 20.5 MB
    short*    vtB = kB  + (size_t)32768 * 256;                // @ 36.5 MB
    short*    avB = vtB + (size_t)32768 * 256;                // @ 52.5 MB (ends 68.5 MB)
    (void)in_sizes; (void)n_in; (void)out_size; (void)ws_size;

    prep_w<<<1024, 256, 0, stream>>>(Wq, Wk, Wv, Wo, Wt);
    mask_pack<<<4096, 256, 0, stream>>>(mask, mpW);
    qkv_gemm<<<1024, 256, 0, stream>>>(x, Wt, bq, bk, bv, qB, kB, vtB);
    attn<<<256, 512, 0, stream>>>(qB, kB, vtB, mpW, avB);
    out_gemm<<<1024, 256, 0, stream>>>(avB, Wt + 3 * 65536, bo, out);
}

// Round 3
// 150.519 us; speedup vs baseline: 2.2467x; 1.0696x over previous
//
#include <hip/hip_runtime.h>

// Pipeline: prep_w -> qkv_gemm (mask-pack prelude + fused Q,K,V; K & V^T written XOR-swizzled)
//           -> attn (flash, double-buffered LDS K/V, counted vmcnt, raw barriers) -> out_gemm
// All matmul compute in bf16 MFMA (16x16x32), f32 accumulate. Output f32.

typedef __attribute__((ext_vector_type(4))) float    f32x4;
typedef __attribute__((ext_vector_type(8))) short    s16x8;
typedef __attribute__((ext_vector_type(4))) short    s16x4;
typedef __attribute__((ext_vector_type(4))) unsigned u32x4;

__device__ __forceinline__ short f2b(float f) {
    union { float f; unsigned u; } v; v.f = f;
    unsigned r = v.u + 0x7FFFu + ((v.u >> 16) & 1u);
    return (short)(r >> 16);
}

__device__ __forceinline__ void gl_lds16(const short* g, short* l) {
    __builtin_amdgcn_global_load_lds(
        (const __attribute__((address_space(1))) unsigned int*)g,
        (__attribute__((address_space(3))) unsigned int*)l, 16, 0, 0);
}

// ---- Wt[w][n][k] = (bf16) W_w[k][n], w order {q,k,v,o} ----
__global__ void prep_w(const float* __restrict__ Wq, const float* __restrict__ Wk,
                       const float* __restrict__ Wv, const float* __restrict__ Wo,
                       short* __restrict__ Wt) {
    int idx = blockIdx.x * 256 + threadIdx.x;       // 4 * 65536 total
    int w = idx >> 16, rem = idx & 65535;
    int n = rem >> 8, kk = rem & 255;
    const float* W = (w == 0) ? Wq : (w == 1) ? Wk : (w == 2) ? Wv : Wo;
    Wt[idx] = f2b(W[kk * 256 + n]);
}

// ---- fused QKV projection: x[32768,256] f32 @ W^T -> relu -> bf16 ----
// Prelude: bit-pack the attention mask (1 bit per element) into mp.
// q stored [seq][h] linear; k stored [seq][h] with 16B-chunk low3 XOR (seq&7);
// v stored transposed Vt[b][h][seq] with 16B-chunk low3 XOR (h&7).
__global__ __launch_bounds__(256) void qkv_gemm(
        const float* __restrict__ x, const short* __restrict__ Wt,
        const float* __restrict__ bq, const float* __restrict__ bk, const float* __restrict__ bv,
        const float* __restrict__ mask, unsigned* __restrict__ mp,
        short* __restrict__ qO, short* __restrict__ kO, short* __restrict__ vtO) {
    __shared__ short a_lds[128][72];        // x tile bf16 (also reused as epilogue bounce)
    __shared__ short b_lds[3][64][72];      // W^T tiles
    const int tid = threadIdx.x;
    const int bm = blockIdx.x >> 2, bn = blockIdx.x & 3;
    const int s0 = bm * 128, n0 = bn * 64;
    const int wid = tid >> 6, l = tid & 63, lo4 = l & 15, hi4 = l >> 4;
    const int wm = wid >> 1, wn = wid & 1;

    // ---- mask bit-pack prelude: 262144 threads x 128 floats -> 4 u32 each ----
    {
        int gid = blockIdx.x * 256 + tid;
        const float* p = mask + (size_t)gid * 128;
        u32x4 ob;
        #pragma unroll
        for (int wgi = 0; wgi < 4; ++wgi) {
            unsigned bb = 0;
            #pragma unroll
            for (int i = 0; i < 8; ++i) {
                f32x4 v = *(const f32x4*)(p + wgi * 32 + i * 4);
                bb |= (unsigned)(v.x != 0.f) << (i * 4);
                bb |= (unsigned)(v.y != 0.f) << (i * 4 + 1);
                bb |= (unsigned)(v.z != 0.f) << (i * 4 + 2);
                bb |= (unsigned)(v.w != 0.f) << (i * 4 + 3);
            }
            ob[wgi] = bb;
        }
        *(u32x4*)(mp + (size_t)gid * 4) = ob;
    }

    f32x4 acc[3][4][2];
    #pragma unroll
    for (int w = 0; w < 3; ++w)
        #pragma unroll
        for (int mi = 0; mi < 4; ++mi)
            #pragma unroll
            for (int ni = 0; ni < 2; ++ni)
                acc[w][mi][ni] = (f32x4){0.f, 0.f, 0.f, 0.f};

    for (int kt = 0; kt < 4; ++kt) {
        const int k0 = kt * 64;
        #pragma unroll
        for (int i = 0; i < 8; ++i) {                       // stage A: 128x64 f32 -> bf16
            int ch = i * 256 + tid;
            int row = ch >> 4, c4 = (ch & 15) * 4;
            f32x4 xv = *(const f32x4*)(x + (size_t)(s0 + row) * 256 + k0 + c4);
            s16x4 pk = { f2b(xv.x), f2b(xv.y), f2b(xv.z), f2b(xv.w) };
            *(s16x4*)&a_lds[row][c4] = pk;
        }
        #pragma unroll
        for (int w = 0; w < 3; ++w) {                       // stage B: 3 x 64x64 bf16
            #pragma unroll
            for (int i = 0; i < 2; ++i) {
                int ch = i * 256 + tid;
                int n = ch >> 3, c8 = (ch & 7) * 8;
                *(s16x8*)&b_lds[w][n][c8] =
                    *(const s16x8*)(Wt + (size_t)w * 65536 + (size_t)(n0 + n) * 256 + k0 + c8);
            }
        }
        __syncthreads();
        s16x8 af[4][2];
        #pragma unroll
        for (int mi = 0; mi < 4; ++mi)
            #pragma unroll
            for (int kk = 0; kk < 2; ++kk)
                af[mi][kk] = *(s16x8*)&a_lds[wm * 64 + mi * 16 + lo4][kk * 32 + hi4 * 8];
        #pragma unroll
        for (int w = 0; w < 3; ++w)
            #pragma unroll
            for (int ni = 0; ni < 2; ++ni)
                #pragma unroll
                for (int kk = 0; kk < 2; ++kk) {
                    s16x8 bfr = *(s16x8*)&b_lds[w][wn * 32 + ni * 16 + lo4][kk * 32 + hi4 * 8];
                    #pragma unroll
                    for (int mi = 0; mi < 4; ++mi)
                        acc[w][mi][ni] = __builtin_amdgcn_mfma_f32_16x16x32_bf16(
                            af[mi][kk], bfr, acc[w][mi][ni], 0, 0, 0);
                }
        __syncthreads();
    }

    const float* bias[3] = { bq, bk, bv };
    for (int w = 0; w < 3; ++w) {
        #pragma unroll
        for (int mi = 0; mi < 4; ++mi)
            #pragma unroll
            for (int ni = 0; ni < 2; ++ni)
                #pragma unroll
                for (int j = 0; j < 4; ++j) {
                    int r = wm * 64 + mi * 16 + hi4 * 4 + j;
                    int c = wn * 32 + ni * 16 + lo4;
                    float v = acc[w][mi][ni][j] + bias[w][n0 + c];
                    a_lds[r][c] = f2b(fmaxf(v, 0.f));
                }
        __syncthreads();
        if (w == 0) {
            #pragma unroll
            for (int i = 0; i < 4; ++i) {
                int ch = i * 256 + tid;
                int row = ch >> 3, c8 = (ch & 7) * 8;
                *(s16x8*)(qO + (size_t)(s0 + row) * 256 + n0 + c8) = *(s16x8*)&a_lds[row][c8];
            }
        } else if (w == 1) {
            #pragma unroll
            for (int i = 0; i < 4; ++i) {
                int ch = i * 256 + tid;
                int row = ch >> 3, c8 = (ch & 7) * 8;
                int swz = ((c8 >> 3) ^ (row & 7)) * 8;      // seq-keyed chunk XOR
                *(s16x8*)(kO + (size_t)(s0 + row) * 256 + n0 + swz) = *(s16x8*)&a_lds[row][c8];
            }
        } else {
            int bb = s0 >> 10, nn = s0 & 1023;              // block spans a single batch
            #pragma unroll
            for (int i = 0; i < 4; ++i) {
                int ch = i * 256 + tid;
                int h = ch >> 4, sc = (ch & 15) * 8;
                s16x8 t;
                #pragma unroll
                for (int e = 0; e < 8; ++e) t[e] = a_lds[sc + e][h];
                int cil = sc >> 3;                          // 0..15
                int swz = (cil & 8) | ((cil & 7) ^ ((n0 + h) & 7));   // h-keyed chunk XOR
                *(s16x8*)(vtO + ((size_t)bb * 256 + n0 + h) * 1024 + nn + swz * 8) = t;
            }
        }
        __syncthreads();
    }
}

// ---- flash attention: 8 waves/block, Q-tile 128, double-buffered K/V, counted vmcnt ----
__global__ __launch_bounds__(512) void attn(
        const short* __restrict__ q, const short* __restrict__ k,
        const short* __restrict__ vt, const unsigned* __restrict__ mp,
        short* __restrict__ attv) {
    __shared__ short kbuf[2][16384];        // 2 x K[64][256] (row-XOR-swizzled layout)
    __shared__ short vbuf[2][16384];        // 2 x V[256][64] (h-XOR-swizzled layout)
    __shared__ short p_lds[8][16][72];      // per-wave P relayout / epilogue bounce
    const int tid = threadIdx.x, wid = tid >> 6, l = tid & 63;
    const int lo4 = l & 15, hi4 = l >> 4;
    const int bid = blockIdx.x;
    const int swz = (bid & 7) * 32 + (bid >> 3);    // XCD-chunked: 4 batches per XCD
    const int b = swz >> 3, qb = swz & 7;
    const int q0 = qb * 128 + wid * 16;
    const size_t bq_row = (size_t)b * 1024 + q0;

    const short* kb  = k  + (size_t)b * 1024 * 256;
    const short* vtg = vt + (size_t)b * 256 * 1024;
    const unsigned* mpb = mp + ((size_t)b << 15);

#define STAGE_K(bufi, c0_) do { const short* sg_ = kb + (size_t)(c0_) * 256;          \
    _Pragma("unroll") for (int i_ = 0; i_ < 4; ++i_) { int cb_ = i_ * 512 + wid * 64; \
        gl_lds16(sg_ + (size_t)(cb_ + l) * 8, &kbuf[bufi][cb_ * 8]); } } while (0)
#define STAGE_V(bufi, c0_) do {                                                       \
    _Pragma("unroll") for (int i_ = 0; i_ < 4; ++i_) { int cb_ = i_ * 512 + wid * 64; \
        int ch_ = cb_ + l; int h_ = ch_ >> 3, cc_ = ch_ & 7;                          \
        gl_lds16(vtg + (size_t)h_ * 1024 + (c0_) + cc_ * 8, &vbuf[bufi][cb_ * 8]); } } while (0)
#define LOAD_MASK(dst, c0_) do {                                                      \
    _Pragma("unroll") for (int j_ = 0; j_ < 4; ++j_) {                                \
        size_t wi_ = (size_t)(q0 + hi4 * 4 + j_) * 32 + ((c0_) >> 5);                 \
        dst[j_ * 2] = mpb[wi_]; dst[j_ * 2 + 1] = mpb[wi_ + 1]; } } while (0)

    s16x8 qf[8];
    {
        const short* qp = q + (bq_row + lo4) * 256 + hi4 * 8;
        #pragma unroll
        for (int t = 0; t < 8; ++t) qf[t] = *(const s16x8*)(qp + t * 32);
    }
    f32x4 oacc[16];
    #pragma unroll
    for (int t = 0; t < 16; ++t) oacc[t] = (f32x4){0.f, 0.f, 0.f, 0.f};
    float m_run[4] = { -1e30f, -1e30f, -1e30f, -1e30f };
    float l_run[4] = { 0.f, 0.f, 0.f, 0.f };
    unsigned mwc[8], mwn[8];

    // prologue: stage tile 0 (K: 4 loads, mask: 8, V: 4)
    STAGE_K(0, 0);
    LOAD_MASK(mwc, 0);
    STAGE_V(0, 0);

    for (int t = 0; t < 16; ++t) {
        const int cur = t & 1;
        const int c0 = t * 64;
        // ---- issue next K stage + next mask, then wait for K[t] (counted) ----
        if (t < 15) {
            STAGE_K(cur ^ 1, c0 + 64);                      // +4 vmem
            LOAD_MASK(mwn, c0 + 64);                        // +8 vmem
            // younger-than-K[t]: mask[t](8) + V[t](4) + K[t+1](4) + mask[t+1](8) = 24
            asm volatile("s_waitcnt vmcnt(24)" ::: "memory");
        } else {
            // younger-than-K[15]: mask[15](8) + V[15](4) = 12
            asm volatile("s_waitcnt vmcnt(12)" ::: "memory");
        }
        __builtin_amdgcn_s_barrier();
        // ---- QK^T on kbuf[cur] ----
        f32x4 s[4];
        #pragma unroll
        for (int ct = 0; ct < 4; ++ct) s[ct] = (f32x4){0.f, 0.f, 0.f, 0.f};
        __builtin_amdgcn_s_setprio(1);
        #pragma unroll
        for (int ct = 0; ct < 4; ++ct) {
            int row = ct * 16 + lo4, rx = row & 7;
            #pragma unroll
            for (int tt = 0; tt < 8; ++tt) {
                int ch = tt * 4 + hi4;
                int sc = (ch & 24) | ((ch & 7) ^ rx);
                s16x8 kf = *(s16x8*)&kbuf[cur][row * 256 + sc * 8];
                s[ct] = __builtin_amdgcn_mfma_f32_16x16x32_bf16(qf[tt], kf, s[ct], 0, 0, 0);
            }
        }
        __builtin_amdgcn_s_setprio(0);
        // ---- masked online softmax (mask bits in regs) ----
        float sm[4][4];
        #pragma unroll
        for (int j = 0; j < 4; ++j) {
            unsigned w0 = mwc[j * 2], w1 = mwc[j * 2 + 1];
            sm[0][j] = ((w0 >> lo4) & 1)        ? s[0][j] : -1e30f;
            sm[1][j] = ((w0 >> (16 + lo4)) & 1) ? s[1][j] : -1e30f;
            sm[2][j] = ((w1 >> lo4) & 1)        ? s[2][j] : -1e30f;
            sm[3][j] = ((w1 >> (16 + lo4)) & 1) ? s[3][j] : -1e30f;
        }
        float scale[4], p[4][4];
        #pragma unroll
        for (int j = 0; j < 4; ++j) {
            float tmx = fmaxf(fmaxf(sm[0][j], sm[1][j]), fmaxf(sm[2][j], sm[3][j]));
            tmx = fmaxf(tmx, __shfl_xor(tmx, 1));
            tmx = fmaxf(tmx, __shfl_xor(tmx, 2));
            tmx = fmaxf(tmx, __shfl_xor(tmx, 4));
            tmx = fmaxf(tmx, __shfl_xor(tmx, 8));
            float mnew = fmaxf(m_run[j], tmx);
            scale[j] = __expf(m_run[j] - mnew);
            m_run[j] = mnew;
            float su = 0.f;
            #pragma unroll
            for (int ct = 0; ct < 4; ++ct) { p[ct][j] = __expf(sm[ct][j] - mnew); su += p[ct][j]; }
            su += __shfl_xor(su, 1);
            su += __shfl_xor(su, 2);
            su += __shfl_xor(su, 4);
            su += __shfl_xor(su, 8);
            l_run[j] = l_run[j] * scale[j] + su;
        }
        #pragma unroll
        for (int tt = 0; tt < 16; ++tt)
            #pragma unroll
            for (int j = 0; j < 4; ++j) oacc[tt][j] *= scale[j];
        // ---- P (D-layout) -> per-wave LDS -> A-fragment ----
        #pragma unroll
        for (int ct = 0; ct < 4; ++ct)
            #pragma unroll
            for (int j = 0; j < 4; ++j)
                p_lds[wid][hi4 * 4 + j][ct * 16 + lo4] = f2b(p[ct][j]);
        asm volatile("s_waitcnt lgkmcnt(0)" ::: "memory");
        __builtin_amdgcn_sched_barrier(0);
        s16x8 pa0 = *(s16x8*)&p_lds[wid][lo4][hi4 * 8];
        s16x8 pa1 = *(s16x8*)&p_lds[wid][lo4][32 + hi4 * 8];
        // ---- issue next V stage, then wait for V[t] (counted) ----
        if (t < 15) {
            STAGE_V(cur ^ 1, c0 + 64);                      // +4 vmem
            // younger-than-V[t]: K[t+1](4) + mask[t+1](8) + V[t+1](4) = 16
            asm volatile("s_waitcnt vmcnt(16)" ::: "memory");
        } else {
            asm volatile("s_waitcnt vmcnt(0)" ::: "memory");
        }
        __builtin_amdgcn_s_barrier();
        // ---- PV on vbuf[cur] ----
        __builtin_amdgcn_s_setprio(1);
        #pragma unroll
        for (int nt = 0; nt < 16; ++nt) {
            int h = nt * 16 + lo4, hx = h & 7;
            s16x8 vf0 = *(s16x8*)&vbuf[cur][h * 64 + (hi4 ^ hx) * 8];
            s16x8 vf1 = *(s16x8*)&vbuf[cur][h * 64 + ((hi4 + 4) ^ hx) * 8];
            oacc[nt] = __builtin_amdgcn_mfma_f32_16x16x32_bf16(pa0, vf0, oacc[nt], 0, 0, 0);
            oacc[nt] = __builtin_amdgcn_mfma_f32_16x16x32_bf16(pa1, vf1, oacc[nt], 0, 0, 0);
        }
        __builtin_amdgcn_s_setprio(0);
        // ---- rotate mask regs ----
        if (t < 15) {
            #pragma unroll
            for (int i = 0; i < 8; ++i) mwc[i] = mwn[i];
        }
    }
    // ---- epilogue: normalize, bf16, coalesced store via per-wave LDS (4 passes) ----
    float inv[4];
    #pragma unroll
    for (int j = 0; j < 4; ++j) inv[j] = 1.f / l_run[j];
    #pragma unroll
    for (int g = 0; g < 4; ++g) {
        asm volatile("s_waitcnt lgkmcnt(0)" ::: "memory");  // prior pass reads done
        #pragma unroll
        for (int ntl = 0; ntl < 4; ++ntl)
            #pragma unroll
            for (int j = 0; j < 4; ++j)
                p_lds[wid][hi4 * 4 + j][ntl * 16 + lo4] = f2b(oacc[g * 4 + ntl][j] * inv[j]);
        asm volatile("s_waitcnt lgkmcnt(0)" ::: "memory");
        __builtin_amdgcn_sched_barrier(0);
        s16x8 r0 = *(s16x8*)&p_lds[wid][lo4][hi4 * 16];
        s16x8 r1 = *(s16x8*)&p_lds[wid][lo4][hi4 * 16 + 8];
        short* op = attv + (bq_row + lo4) * 256 + g * 64 + hi4 * 16;
        *(s16x8*)op = r0;
        *(s16x8*)(op + 8) = r1;
    }
#undef STAGE_K
#undef STAGE_V
#undef LOAD_MASK
}

// ---- output GEMM: attv bf16 @ Wo^T + bo -> relu -> f32 ----
__global__ __launch_bounds__(256) void out_gemm(
        const short* __restrict__ a, const short* __restrict__ Wto,
        const float* __restrict__ bo, float* __restrict__ out) {
    __shared__ short a_lds[128][72];
    __shared__ short b_lds[64][72];
    __shared__ float bounce[128][68];
    const int tid = threadIdx.x;
    const int bm = blockIdx.x >> 2, bn = blockIdx.x & 3;
    const int s0 = bm * 128, n0 = bn * 64;
    const int wid = tid >> 6, l = tid & 63, lo4 = l & 15, hi4 = l >> 4;
    const int wm = wid >> 1, wn = wid & 1;
    f32x4 acc[4][2];
    #pragma unroll
    for (int mi = 0; mi < 4; ++mi)
        #pragma unroll
        for (int ni = 0; ni < 2; ++ni) acc[mi][ni] = (f32x4){0.f, 0.f, 0.f, 0.f};

    for (int kt = 0; kt < 4; ++kt) {
        const int k0 = kt * 64;
        #pragma unroll
        for (int i = 0; i < 4; ++i) {
            int ch = i * 256 + tid;
            int row = ch >> 3, c8 = (ch & 7) * 8;
            *(s16x8*)&a_lds[row][c8] = *(const s16x8*)(a + (size_t)(s0 + row) * 256 + k0 + c8);
        }
        #pragma unroll
        for (int i = 0; i < 2; ++i) {
            int ch = i * 256 + tid;
            int n = ch >> 3, c8 = (ch & 7) * 8;
            *(s16x8*)&b_lds[n][c8] = *(const s16x8*)(Wto + (size_t)(n0 + n) * 256 + k0 + c8);
        }
        __syncthreads();
        s16x8 af[4][2];
        #pragma unroll
        for (int mi = 0; mi < 4; ++mi)
            #pragma unroll
            for (int kk = 0; kk < 2; ++kk)
                af[mi][kk] = *(s16x8*)&a_lds[wm * 64 + mi * 16 + lo4][kk * 32 + hi4 * 8];
        #pragma unroll
        for (int ni = 0; ni < 2; ++ni)
            #pragma unroll
            for (int kk = 0; kk < 2; ++kk) {
                s16x8 bfr = *(s16x8*)&b_lds[wn * 32 + ni * 16 + lo4][kk * 32 + hi4 * 8];
                #pragma unroll
                for (int mi = 0; mi < 4; ++mi)
                    acc[mi][ni] = __builtin_amdgcn_mfma_f32_16x16x32_bf16(
                        af[mi][kk], bfr, acc[mi][ni], 0, 0, 0);
            }
        __syncthreads();
    }
    #pragma unroll
    for (int mi = 0; mi < 4; ++mi)
        #pragma unroll
        for (int ni = 0; ni < 2; ++ni)
            #pragma unroll
            for (int j = 0; j < 4; ++j) {
                int r = wm * 64 + mi * 16 + hi4 * 4 + j;
                int c = wn * 32 + ni * 16 + lo4;
                bounce[r][c] = fmaxf(acc[mi][ni][j] + bo[n0 + c], 0.f);
            }
    __syncthreads();
    #pragma unroll
    for (int i = 0; i < 8; ++i) {
        int ch = i * 256 + tid;
        int row = ch >> 4, c4 = (ch & 15) * 4;
        *(f32x4*)(out + (size_t)(s0 + row) * 256 + n0 + c4) = *(f32x4*)&bounce[row][c4];
    }
}

extern "C" void kernel_launch(void* const* d_in, const int* in_sizes, int n_in,
                              void* d_out, int out_size, void* d_ws, size_t ws_size,
                              hipStream_t stream) {
    const float* x    = (const float*)d_in[0];
    const float* mask = (const float*)d_in[1];
    const float* Wv   = (const float*)d_in[2];
    const float* bv   = (const float*)d_in[3];
    const float* Wk   = (const float*)d_in[4];
    const float* bk   = (const float*)d_in[5];
    const float* Wq   = (const float*)d_in[6];
    const float* bq   = (const float*)d_in[7];
    const float* Wo   = (const float*)d_in[8];
    const float* bo   = (const float*)d_in[9];
    float* out = (float*)d_out;

    char* ws = (char*)d_ws;
    short*    Wt  = (short*)ws;                               // 512 KB @ 0
    unsigned* mpW = (unsigned*)(ws + (512 << 10));            // 4 MB  @ 0.5 MB
    short*    qB  = (short*)(ws + (4608 << 10));              // 16 MB @ 4.5 MB
    short*    kB  = qB  + (size_t)32768 * 256;                // @ 20.5 MB
    short*    vtB = kB  + (size_t)32768 * 256;                // @ 36.5 MB
    short*    avB = vtB + (size_t)32768 * 256;                // @ 52.5 MB (ends 68.5 MB)
    (void)in_sizes; (void)n_in; (void)out_size; (void)ws_size;

    prep_w<<<1024, 256, 0, stream>>>(Wq, Wk, Wv, Wo, Wt);
    qkv_gemm<<<1024, 256, 0, stream>>>(x, Wt, bq, bk, bv, mask, mpW, qB, kB, vtB);
    attn<<<256, 512, 0, stream>>>(qB, kB, vtB, mpW, avB);
    out_gemm<<<1024, 256, 0, stream>>>(avB, Wt + 3 * 65536, bo, out);
}

// Round 4
// 147.167 us; speedup vs baseline: 2.2979x; 1.0228x over previous
//
#include <hip/hip_runtime.h>

// Pipeline: prep_w -> qkv_gemm (coalesced ballot-style mask-pack prelude + fused Q,K,V;
//           K & V^T written XOR-swizzled) -> attn (flash, dbuf LDS K/V, counted vmcnt) -> out_gemm
// All matmul compute in bf16 MFMA (16x16x32), f32 accumulate. Output f32.

typedef __attribute__((ext_vector_type(4))) float    f32x4;
typedef __attribute__((ext_vector_type(8))) short    s16x8;
typedef __attribute__((ext_vector_type(4))) short    s16x4;

__device__ __forceinline__ short f2b(float f) {
    union { float f; unsigned u; } v; v.f = f;
    unsigned r = v.u + 0x7FFFu + ((v.u >> 16) & 1u);
    return (short)(r >> 16);
}

__device__ __forceinline__ void gl_lds16(const short* g, short* l) {
    __builtin_amdgcn_global_load_lds(
        (const __attribute__((address_space(1))) unsigned int*)g,
        (__attribute__((address_space(3))) unsigned int*)l, 16, 0, 0);
}

// ---- Wt[w][n][k] = (bf16) W_w[k][n], w order {q,k,v,o} ----
__global__ void prep_w(const float* __restrict__ Wq, const float* __restrict__ Wk,
                       const float* __restrict__ Wv, const float* __restrict__ Wo,
                       short* __restrict__ Wt) {
    int idx = blockIdx.x * 256 + threadIdx.x;       // 4 * 65536 total
    int w = idx >> 16, rem = idx & 65535;
    int n = rem >> 8, kk = rem & 255;
    const float* W = (w == 0) ? Wq : (w == 1) ? Wk : (w == 2) ? Wv : Wo;
    Wt[idx] = f2b(W[kk * 256 + n]);
}

// ---- fused QKV projection: x[32768,256] f32 @ W^T -> relu -> bf16 ----
// Prelude: bit-pack the attention mask (1 bit per element), lane-coalesced loads +
// 8-lane shuffle-OR word assembly, double-buffered sets.
// q stored [seq][h] linear; k stored [seq][h] with 16B-chunk low3 XOR (seq&7);
// v stored transposed Vt[b][h][seq] with 16B-chunk low3 XOR (h&7).
__global__ __launch_bounds__(256) void qkv_gemm(
        const float* __restrict__ x, const short* __restrict__ Wt,
        const float* __restrict__ bq, const float* __restrict__ bk, const float* __restrict__ bv,
        const float* __restrict__ mask, unsigned* __restrict__ mp,
        short* __restrict__ qO, short* __restrict__ kO, short* __restrict__ vtO) {
    __shared__ short a_lds[128][72];        // x tile bf16 (also reused as epilogue bounce)
    __shared__ short b_lds[3][64][72];      // W^T tiles
    const int tid = threadIdx.x;
    const int bm = blockIdx.x >> 2, bn = blockIdx.x & 3;
    const int s0 = bm * 128, n0 = bn * 64;
    const int wid = tid >> 6, l = tid & 63, lo4 = l & 15, hi4 = l >> 4;
    const int wm = wid >> 1, wn = wid & 1;

    // ---- mask bit-pack prelude: each wave packs 4 sets of 2048 elements ----
    // Round r: lane loads f32x4 (1KB/wave contiguous). nibble -> 8-lane shuffle-OR ->
    // word for elements [256r+32g, +32), g = lane>>3. Lane keeps round r==lane&7;
    // final store: word index 8*(lane&7) + (lane>>3)  (coalesced 256B segment).
    {
        const size_t eBase = (size_t)blockIdx.x * 32768 + (size_t)wid * 2048;
        unsigned* wpB = mp + (size_t)blockIdx.x * 1024 + wid * 64 + ((l & 7) << 3) + (l >> 3);
        f32x4 va[8], vb[8];
#define LOAD_SET(BUF, S2) do { const float* pn_ = mask + eBase + (S2) * 8192;          \
    _Pragma("unroll") for (int r_ = 0; r_ < 8; ++r_)                                   \
        BUF[r_] = *(const f32x4*)(pn_ + r_ * 256 + l * 4); } while (0)
#define PACK_SET(BUF, S2) do { unsigned kw_ = 0;                                       \
    _Pragma("unroll") for (int r_ = 0; r_ < 8; ++r_) {                                 \
        unsigned nib_ = (unsigned)(BUF[r_].x != 0.f) | ((unsigned)(BUF[r_].y != 0.f) << 1) \
                      | ((unsigned)(BUF[r_].z != 0.f) << 2) | ((unsigned)(BUF[r_].w != 0.f) << 3); \
        unsigned val_ = nib_ << ((l & 7) * 4);                                         \
        val_ |= (unsigned)__shfl_xor((int)val_, 1);                                    \
        val_ |= (unsigned)__shfl_xor((int)val_, 2);                                    \
        val_ |= (unsigned)__shfl_xor((int)val_, 4);                                    \
        if ((l & 7) == r_) kw_ = val_; }                                               \
    wpB[(S2) * 256] = kw_; } while (0)
        LOAD_SET(va, 0); LOAD_SET(vb, 1);
        PACK_SET(va, 0); LOAD_SET(va, 2);
        PACK_SET(vb, 1); LOAD_SET(vb, 3);
        PACK_SET(va, 2); PACK_SET(vb, 3);
#undef LOAD_SET
#undef PACK_SET
    }

    f32x4 acc[3][4][2];
    #pragma unroll
    for (int w = 0; w < 3; ++w)
        #pragma unroll
        for (int mi = 0; mi < 4; ++mi)
            #pragma unroll
            for (int ni = 0; ni < 2; ++ni)
                acc[w][mi][ni] = (f32x4){0.f, 0.f, 0.f, 0.f};

    for (int kt = 0; kt < 4; ++kt) {
        const int k0 = kt * 64;
        #pragma unroll
        for (int i = 0; i < 8; ++i) {                       // stage A: 128x64 f32 -> bf16
            int ch = i * 256 + tid;
            int row = ch >> 4, c4 = (ch & 15) * 4;
            f32x4 xv = *(const f32x4*)(x + (size_t)(s0 + row) * 256 + k0 + c4);
            s16x4 pk = { f2b(xv.x), f2b(xv.y), f2b(xv.z), f2b(xv.w) };
            *(s16x4*)&a_lds[row][c4] = pk;
        }
        #pragma unroll
        for (int w = 0; w < 3; ++w) {                       // stage B: 3 x 64x64 bf16
            #pragma unroll
            for (int i = 0; i < 2; ++i) {
                int ch = i * 256 + tid;
                int n = ch >> 3, c8 = (ch & 7) * 8;
                *(s16x8*)&b_lds[w][n][c8] =
                    *(const s16x8*)(Wt + (size_t)w * 65536 + (size_t)(n0 + n) * 256 + k0 + c8);
            }
        }
        __syncthreads();
        s16x8 af[4][2];
        #pragma unroll
        for (int mi = 0; mi < 4; ++mi)
            #pragma unroll
            for (int kk = 0; kk < 2; ++kk)
                af[mi][kk] = *(s16x8*)&a_lds[wm * 64 + mi * 16 + lo4][kk * 32 + hi4 * 8];
        #pragma unroll
        for (int w = 0; w < 3; ++w)
            #pragma unroll
            for (int ni = 0; ni < 2; ++ni)
                #pragma unroll
                for (int kk = 0; kk < 2; ++kk) {
                    s16x8 bfr = *(s16x8*)&b_lds[w][wn * 32 + ni * 16 + lo4][kk * 32 + hi4 * 8];
                    #pragma unroll
                    for (int mi = 0; mi < 4; ++mi)
                        acc[w][mi][ni] = __builtin_amdgcn_mfma_f32_16x16x32_bf16(
                            af[mi][kk], bfr, acc[w][mi][ni], 0, 0, 0);
                }
        __syncthreads();
    }

    const float* bias[3] = { bq, bk, bv };
    for (int w = 0; w < 3; ++w) {
        #pragma unroll
        for (int mi = 0; mi < 4; ++mi)
            #pragma unroll
            for (int ni = 0; ni < 2; ++ni)
                #pragma unroll
                for (int j = 0; j < 4; ++j) {
                    int r = wm * 64 + mi * 16 + hi4 * 4 + j;
                    int c = wn * 32 + ni * 16 + lo4;
                    float v = acc[w][mi][ni][j] + bias[w][n0 + c];
                    a_lds[r][c] = f2b(fmaxf(v, 0.f));
                }
        __syncthreads();
        if (w == 0) {
            #pragma unroll
            for (int i = 0; i < 4; ++i) {
                int ch = i * 256 + tid;
                int row = ch >> 3, c8 = (ch & 7) * 8;
                *(s16x8*)(qO + (size_t)(s0 + row) * 256 + n0 + c8) = *(s16x8*)&a_lds[row][c8];
            }
        } else if (w == 1) {
            #pragma unroll
            for (int i = 0; i < 4; ++i) {
                int ch = i * 256 + tid;
                int row = ch >> 3, c8 = (ch & 7) * 8;
                int swz = ((c8 >> 3) ^ (row & 7)) * 8;      // seq-keyed chunk XOR
                *(s16x8*)(kO + (size_t)(s0 + row) * 256 + n0 + swz) = *(s16x8*)&a_lds[row][c8];
            }
        } else {
            int bb = s0 >> 10, nn = s0 & 1023;              // block spans a single batch
            #pragma unroll
            for (int i = 0; i < 4; ++i) {
                int ch = i * 256 + tid;
                int h = ch >> 4, sc = (ch & 15) * 8;
                s16x8 t;
                #pragma unroll
                for (int e = 0; e < 8; ++e) t[e] = a_lds[sc + e][h];
                int cil = sc >> 3;                          // 0..15
                int swz = (cil & 8) | ((cil & 7) ^ ((n0 + h) & 7));   // h-keyed chunk XOR
                *(s16x8*)(vtO + ((size_t)bb * 256 + n0 + h) * 1024 + nn + swz * 8) = t;
            }
        }
        __syncthreads();
    }
}

// ---- flash attention: 8 waves/block, Q-tile 128, double-buffered K/V, counted vmcnt ----
__global__ __launch_bounds__(512) void attn(
        const short* __restrict__ q, const short* __restrict__ k,
        const short* __restrict__ vt, const unsigned* __restrict__ mp,
        short* __restrict__ attv) {
    __shared__ short kbuf[2][16384];        // 2 x K[64][256] (row-XOR-swizzled layout)
    __shared__ short vbuf[2][16384];        // 2 x V[256][64] (h-XOR-swizzled layout)
    __shared__ short p_lds[8][16][72];      // per-wave P relayout / epilogue bounce
    const int tid = threadIdx.x, wid = tid >> 6, l = tid & 63;
    const int lo4 = l & 15, hi4 = l >> 4;
    const int bid = blockIdx.x;
    const int swz = (bid & 7) * 32 + (bid >> 3);    // XCD-chunked: 4 batches per XCD
    const int b = swz >> 3, qb = swz & 7;
    const int q0 = qb * 128 + wid * 16;
    const size_t bq_row = (size_t)b * 1024 + q0;

    const short* kb  = k  + (size_t)b * 1024 * 256;
    const short* vtg = vt + (size_t)b * 256 * 1024;
    const unsigned* mpb = mp + ((size_t)b << 15);

#define STAGE_K(bufi, c0_) do { const short* sg_ = kb + (size_t)(c0_) * 256;          \
    _Pragma("unroll") for (int i_ = 0; i_ < 4; ++i_) { int cb_ = i_ * 512 + wid * 64; \
        gl_lds16(sg_ + (size_t)(cb_ + l) * 8, &kbuf[bufi][cb_ * 8]); } } while (0)
#define STAGE_V(bufi, c0_) do {                                                       \
    _Pragma("unroll") for (int i_ = 0; i_ < 4; ++i_) { int cb_ = i_ * 512 + wid * 64; \
        int ch_ = cb_ + l; int h_ = ch_ >> 3, cc_ = ch_ & 7;                          \
        gl_lds16(vtg + (size_t)h_ * 1024 + (c0_) + cc_ * 8, &vbuf[bufi][cb_ * 8]); } } while (0)
#define LOAD_MASK(dst, c0_) do {                                                      \
    _Pragma("unroll") for (int j_ = 0; j_ < 4; ++j_) {                                \
        size_t wi_ = (size_t)(q0 + hi4 * 4 + j_) * 32 + ((c0_) >> 5);                 \
        dst[j_ * 2] = mpb[wi_]; dst[j_ * 2 + 1] = mpb[wi_ + 1]; } } while (0)

    s16x8 qf[8];
    {
        const short* qp = q + (bq_row + lo4) * 256 + hi4 * 8;
        #pragma unroll
        for (int t = 0; t < 8; ++t) qf[t] = *(const s16x8*)(qp + t * 32);
    }
    f32x4 oacc[16];
    #pragma unroll
    for (int t = 0; t < 16; ++t) oacc[t] = (f32x4){0.f, 0.f, 0.f, 0.f};
    float m_run[4] = { -1e30f, -1e30f, -1e30f, -1e30f };
    float l_run[4] = { 0.f, 0.f, 0.f, 0.f };
    unsigned mwc[8], mwn[8];

    // prologue: stage tile 0 (K: 4 loads, mask: 8, V: 4)
    STAGE_K(0, 0);
    LOAD_MASK(mwc, 0);
    STAGE_V(0, 0);

    for (int t = 0; t < 16; ++t) {
        const int cur = t & 1;
        const int c0 = t * 64;
        // ---- issue next K stage + next mask, then wait for K[t] (counted) ----
        if (t < 15) {
            STAGE_K(cur ^ 1, c0 + 64);                      // +4 vmem
            LOAD_MASK(mwn, c0 + 64);                        // +8 vmem
            // younger-than-K[t]: mask[t](8) + V[t](4) + K[t+1](4) + mask[t+1](8) = 24
            asm volatile("s_waitcnt vmcnt(24)" ::: "memory");
        } else {
            // younger-than-K[15]: mask[15](8) + V[15](4) = 12
            asm volatile("s_waitcnt vmcnt(12)" ::: "memory");
        }
        __builtin_amdgcn_s_barrier();
        // ---- QK^T on kbuf[cur] ----
        f32x4 s[4];
        #pragma unroll
        for (int ct = 0; ct < 4; ++ct) s[ct] = (f32x4){0.f, 0.f, 0.f, 0.f};
        __builtin_amdgcn_s_setprio(1);
        #pragma unroll
        for (int ct = 0; ct < 4; ++ct) {
            int row = ct * 16 + lo4, rx = row & 7;
            #pragma unroll
            for (int tt = 0; tt < 8; ++tt) {
                int ch = tt * 4 + hi4;
                int sc = (ch & 24) | ((ch & 7) ^ rx);
                s16x8 kf = *(s16x8*)&kbuf[cur][row * 256 + sc * 8];
                s[ct] = __builtin_amdgcn_mfma_f32_16x16x32_bf16(qf[tt], kf, s[ct], 0, 0, 0);
            }
        }
        __builtin_amdgcn_s_setprio(0);
        // ---- masked online softmax (mask bits in regs) ----
        float sm[4][4];
        #pragma unroll
        for (int j = 0; j < 4; ++j) {
            unsigned w0 = mwc[j * 2], w1 = mwc[j * 2 + 1];
            sm[0][j] = ((w0 >> lo4) & 1)        ? s[0][j] : -1e30f;
            sm[1][j] = ((w0 >> (16 + lo4)) & 1) ? s[1][j] : -1e30f;
            sm[2][j] = ((w1 >> lo4) & 1)        ? s[2][j] : -1e30f;
            sm[3][j] = ((w1 >> (16 + lo4)) & 1) ? s[3][j] : -1e30f;
        }
        float scale[4], p[4][4];
        #pragma unroll
        for (int j = 0; j < 4; ++j) {
            float tmx = fmaxf(fmaxf(sm[0][j], sm[1][j]), fmaxf(sm[2][j], sm[3][j]));
            tmx = fmaxf(tmx, __shfl_xor(tmx, 1));
            tmx = fmaxf(tmx, __shfl_xor(tmx, 2));
            tmx = fmaxf(tmx, __shfl_xor(tmx, 4));
            tmx = fmaxf(tmx, __shfl_xor(tmx, 8));
            float mnew = fmaxf(m_run[j], tmx);
            scale[j] = __expf(m_run[j] - mnew);
            m_run[j] = mnew;
            float su = 0.f;
            #pragma unroll
            for (int ct = 0; ct < 4; ++ct) { p[ct][j] = __expf(sm[ct][j] - mnew); su += p[ct][j]; }
            su += __shfl_xor(su, 1);
            su += __shfl_xor(su, 2);
            su += __shfl_xor(su, 4);
            su += __shfl_xor(su, 8);
            l_run[j] = l_run[j] * scale[j] + su;
        }
        #pragma unroll
        for (int tt = 0; tt < 16; ++tt)
            #pragma unroll
            for (int j = 0; j < 4; ++j) oacc[tt][j] *= scale[j];
        // ---- P (D-layout) -> per-wave LDS -> A-fragment ----
        #pragma unroll
        for (int ct = 0; ct < 4; ++ct)
            #pragma unroll
            for (int j = 0; j < 4; ++j)
                p_lds[wid][hi4 * 4 + j][ct * 16 + lo4] = f2b(p[ct][j]);
        asm volatile("s_waitcnt lgkmcnt(0)" ::: "memory");
        __builtin_amdgcn_sched_barrier(0);
        s16x8 pa0 = *(s16x8*)&p_lds[wid][lo4][hi4 * 8];
        s16x8 pa1 = *(s16x8*)&p_lds[wid][lo4][32 + hi4 * 8];
        // ---- issue next V stage, then wait for V[t] (counted) ----
        if (t < 15) {
            STAGE_V(cur ^ 1, c0 + 64);                      // +4 vmem
            // younger-than-V[t]: K[t+1](4) + mask[t+1](8) + V[t+1](4) = 16
            asm volatile("s_waitcnt vmcnt(16)" ::: "memory");
        } else {
            asm volatile("s_waitcnt vmcnt(0)" ::: "memory");
        }
        __builtin_amdgcn_s_barrier();
        // ---- PV on vbuf[cur] ----
        __builtin_amdgcn_s_setprio(1);
        #pragma unroll
        for (int nt = 0; nt < 16; ++nt) {
            int h = nt * 16 + lo4, hx = h & 7;
            s16x8 vf0 = *(s16x8*)&vbuf[cur][h * 64 + (hi4 ^ hx) * 8];
            s16x8 vf1 = *(s16x8*)&vbuf[cur][h * 64 + ((hi4 + 4) ^ hx) * 8];
            oacc[nt] = __builtin_amdgcn_mfma_f32_16x16x32_bf16(pa0, vf0, oacc[nt], 0, 0, 0);
            oacc[nt] = __builtin_amdgcn_mfma_f32_16x16x32_bf16(pa1, vf1, oacc[nt], 0, 0, 0);
        }
        __builtin_amdgcn_s_setprio(0);
        // ---- rotate mask regs ----
        if (t < 15) {
            #pragma unroll
            for (int i = 0; i < 8; ++i) mwc[i] = mwn[i];
        }
    }
    // ---- epilogue: normalize, bf16, coalesced store via per-wave LDS (4 passes) ----
    float inv[4];
    #pragma unroll
    for (int j = 0; j < 4; ++j) inv[j] = 1.f / l_run[j];
    #pragma unroll
    for (int g = 0; g < 4; ++g) {
        asm volatile("s_waitcnt lgkmcnt(0)" ::: "memory");  // prior pass reads done
        #pragma unroll
        for (int ntl = 0; ntl < 4; ++ntl)
            #pragma unroll
            for (int j = 0; j < 4; ++j)
                p_lds[wid][hi4 * 4 + j][ntl * 16 + lo4] = f2b(oacc[g * 4 + ntl][j] * inv[j]);
        asm volatile("s_waitcnt lgkmcnt(0)" ::: "memory");
        __builtin_amdgcn_sched_barrier(0);
        s16x8 r0 = *(s16x8*)&p_lds[wid][lo4][hi4 * 16];
        s16x8 r1 = *(s16x8*)&p_lds[wid][lo4][hi4 * 16 + 8];
        short* op = attv + (bq_row + lo4) * 256 + g * 64 + hi4 * 16;
        *(s16x8*)op = r0;
        *(s16x8*)(op + 8) = r1;
    }
#undef STAGE_K
#undef STAGE_V
#undef LOAD_MASK
}

// ---- output GEMM: attv bf16 @ Wo^T + bo -> relu -> f32 ----
__global__ __launch_bounds__(256) void out_gemm(
        const short* __restrict__ a, const short* __restrict__ Wto,
        const float* __restrict__ bo, float* __restrict__ out) {
    __shared__ short a_lds[128][72];
    __shared__ short b_lds[64][72];
    __shared__ float bounce[128][68];
    const int tid = threadIdx.x;
    const int bm = blockIdx.x >> 2, bn = blockIdx.x & 3;
    const int s0 = bm * 128, n0 = bn * 64;
    const int wid = tid >> 6, l = tid & 63, lo4 = l & 15, hi4 = l >> 4;
    const int wm = wid >> 1, wn = wid & 1;
    f32x4 acc[4][2];
    #pragma unroll
    for (int mi = 0; mi < 4; ++mi)
        #pragma unroll
        for (int ni = 0; ni < 2; ++ni) acc[mi][ni] = (f32x4){0.f, 0.f, 0.f, 0.f};

    for (int kt = 0; kt < 4; ++kt) {
        const int k0 = kt * 64;
        #pragma unroll
        for (int i = 0; i < 4; ++i) {
            int ch = i * 256 + tid;
            int row = ch >> 3, c8 = (ch & 7) * 8;
            *(s16x8*)&a_lds[row][c8] = *(const s16x8*)(a + (size_t)(s0 + row) * 256 + k0 + c8);
        }
        #pragma unroll
        for (int i = 0; i < 2; ++i) {
            int ch = i * 256 + tid;
            int n = ch >> 3, c8 = (ch & 7) * 8;
            *(s16x8*)&b_lds[n][c8] = *(const s16x8*)(Wto + (size_t)(n0 + n) * 256 + k0 + c8);
        }
        __syncthreads();
        s16x8 af[4][2];
        #pragma unroll
        for (int mi = 0; mi < 4; ++mi)
            #pragma unroll
            for (int kk = 0; kk < 2; ++kk)
                af[mi][kk] = *(s16x8*)&a_lds[wm * 64 + mi * 16 + lo4][kk * 32 + hi4 * 8];
        #pragma unroll
        for (int ni = 0; ni < 2; ++ni)
            #pragma unroll
            for (int kk = 0; kk < 2; ++kk) {
                s16x8 bfr = *(s16x8*)&b_lds[wn * 32 + ni * 16 + lo4][kk * 32 + hi4 * 8];
                #pragma unroll
                for (int mi = 0; mi < 4; ++mi)
                    acc[mi][ni] = __builtin_amdgcn_mfma_f32_16x16x32_bf16(
                        af[mi][kk], bfr, acc[mi][ni], 0, 0, 0);
            }
        __syncthreads();
    }
    #pragma unroll
    for (int mi = 0; mi < 4; ++mi)
        #pragma unroll
        for (int ni = 0; ni < 2; ++ni)
            #pragma unroll
            for (int j = 0; j < 4; ++j) {
                int r = wm * 64 + mi * 16 + hi4 * 4 + j;
                int c = wn * 32 + ni * 16 + lo4;
                bounce[r][c] = fmaxf(acc[mi][ni][j] + bo[n0 + c], 0.f);
            }
    __syncthreads();
    #pragma unroll
    for (int i = 0; i < 8; ++i) {
        int ch = i * 256 + tid;
        int row = ch >> 4, c4 = (ch & 15) * 4;
        *(f32x4*)(out + (size_t)(s0 + row) * 256 + n0 + c4) = *(f32x4*)&bounce[row][c4];
    }
}

extern "C" void kernel_launch(void* const* d_in, const int* in_sizes, int n_in,
                              void* d_out, int out_size, void* d_ws, size_t ws_size,
                              hipStream_t stream) {
    const float* x    = (const float*)d_in[0];
    const float* mask = (const float*)d_in[1];
    const float* Wv   = (const float*)d_in[2];
    const float* bv   = (const float*)d_in[3];
    const float* Wk   = (const float*)d_in[4];
    const float* bk   = (const float*)d_in[5];
    const float* Wq   = (const float*)d_in[6];
    const float* bq   = (const float*)d_in[7];
    const float* Wo   = (const float*)d_in[8];
    const float* bo   = (const float*)d_in[9];
    float* out = (float*)d_out;

    char* ws = (char*)d_ws;
    short*    Wt  = (short*)ws;                               // 512 KB @ 0
    unsigned* mpW = (unsigned*)(ws + (512 << 10));            // 4 MB  @ 0.5 MB
    short*    qB  = (short*)(ws + (4608 << 10));              // 16 MB @ 4.5 MB
    short*    kB  = qB  + (size_t)32768 * 256;                // @ 20.5 MB
    short*    vtB = kB  + (size_t)32768 * 256;                // @ 36.5 MB
    short*    avB = vtB + (size_t)32768 * 256;                // @ 52.5 MB (ends 68.5 MB)
    (void)in_sizes; (void)n_in; (void)out_size; (void)ws_size;

    prep_w<<<1024, 256, 0, stream>>>(Wq, Wk, Wv, Wo, Wt);
    qkv_gemm<<<1024, 256, 0, stream>>>(x, Wt, bq, bk, bv, mask, mpW, qB, kB, vtB);
    attn<<<256, 512, 0, stream>>>(qB, kB, vtB, mpW, avB);
    out_gemm<<<1024, 256, 0, stream>>>(avB, Wt + 3 * 65536, bo, out);
}

// Round 5
// 138.543 us; speedup vs baseline: 2.4409x; 1.0622x over previous
//
#include <hip/hip_runtime.h>

// Pipeline: prep_w -> qkv_gemm (fused Q,K,V; K & V^T written XOR-swizzled)
//           -> attn (flash, dbuf LDS K/V + counted vmcnt; raw f32 mask streamed
//              through the same prefetch pipeline) -> out_gemm
// All matmul compute in bf16 MFMA (16x16x32), f32 accumulate. Output f32.

typedef __attribute__((ext_vector_type(4))) float    f32x4;
typedef __attribute__((ext_vector_type(8))) short    s16x8;
typedef __attribute__((ext_vector_type(4))) short    s16x4;

__device__ __forceinline__ short f2b(float f) {
    union { float f; unsigned u; } v; v.f = f;
    unsigned r = v.u + 0x7FFFu + ((v.u >> 16) & 1u);
    return (short)(r >> 16);
}

__device__ __forceinline__ void gl_lds16(const short* g, short* l) {
    __builtin_amdgcn_global_load_lds(
        (const __attribute__((address_space(1))) unsigned int*)g,
        (__attribute__((address_space(3))) unsigned int*)l, 16, 0, 0);
}

// ---- Wt[w][n][k] = (bf16) W_w[k][n], w order {q,k,v,o} ----
__global__ void prep_w(const float* __restrict__ Wq, const float* __restrict__ Wk,
                       const float* __restrict__ Wv, const float* __restrict__ Wo,
                       short* __restrict__ Wt) {
    int idx = blockIdx.x * 256 + threadIdx.x;       // 4 * 65536 total
    int w = idx >> 16, rem = idx & 65535;
    int n = rem >> 8, kk = rem & 255;
    const float* W = (w == 0) ? Wq : (w == 1) ? Wk : (w == 2) ? Wv : Wo;
    Wt[idx] = f2b(W[kk * 256 + n]);
}

// ---- fused QKV projection: x[32768,256] f32 @ W^T -> relu -> bf16 ----
// q stored [seq][h] linear; k stored [seq][h] with 16B-chunk low3 XOR (seq&7);
// v stored transposed Vt[b][h][seq] with 16B-chunk low3 XOR (h&7).
__global__ __launch_bounds__(256) void qkv_gemm(
        const float* __restrict__ x, const short* __restrict__ Wt,
        const float* __restrict__ bq, const float* __restrict__ bk, const float* __restrict__ bv,
        short* __restrict__ qO, short* __restrict__ kO, short* __restrict__ vtO) {
    __shared__ short a_lds[128][72];        // x tile bf16 (also reused as epilogue bounce)
    __shared__ short b_lds[3][64][72];      // W^T tiles
    const int tid = threadIdx.x;
    const int bm = blockIdx.x >> 2, bn = blockIdx.x & 3;
    const int s0 = bm * 128, n0 = bn * 64;
    const int wid = tid >> 6, l = tid & 63, lo4 = l & 15, hi4 = l >> 4;
    const int wm = wid >> 1, wn = wid & 1;

    f32x4 acc[3][4][2];
    #pragma unroll
    for (int w = 0; w < 3; ++w)
        #pragma unroll
        for (int mi = 0; mi < 4; ++mi)
            #pragma unroll
            for (int ni = 0; ni < 2; ++ni)
                acc[w][mi][ni] = (f32x4){0.f, 0.f, 0.f, 0.f};

    for (int kt = 0; kt < 4; ++kt) {
        const int k0 = kt * 64;
        #pragma unroll
        for (int i = 0; i < 8; ++i) {                       // stage A: 128x64 f32 -> bf16
            int ch = i * 256 + tid;
            int row = ch >> 4, c4 = (ch & 15) * 4;
            f32x4 xv = *(const f32x4*)(x + (size_t)(s0 + row) * 256 + k0 + c4);
            s16x4 pk = { f2b(xv.x), f2b(xv.y), f2b(xv.z), f2b(xv.w) };
            *(s16x4*)&a_lds[row][c4] = pk;
        }
        #pragma unroll
        for (int w = 0; w < 3; ++w) {                       // stage B: 3 x 64x64 bf16
            #pragma unroll
            for (int i = 0; i < 2; ++i) {
                int ch = i * 256 + tid;
                int n = ch >> 3, c8 = (ch & 7) * 8;
                *(s16x8*)&b_lds[w][n][c8] =
                    *(const s16x8*)(Wt + (size_t)w * 65536 + (size_t)(n0 + n) * 256 + k0 + c8);
            }
        }
        __syncthreads();
        s16x8 af[4][2];
        #pragma unroll
        for (int mi = 0; mi < 4; ++mi)
            #pragma unroll
            for (int kk = 0; kk < 2; ++kk)
                af[mi][kk] = *(s16x8*)&a_lds[wm * 64 + mi * 16 + lo4][kk * 32 + hi4 * 8];
        #pragma unroll
        for (int w = 0; w < 3; ++w)
            #pragma unroll
            for (int ni = 0; ni < 2; ++ni)
                #pragma unroll
                for (int kk = 0; kk < 2; ++kk) {
                    s16x8 bfr = *(s16x8*)&b_lds[w][wn * 32 + ni * 16 + lo4][kk * 32 + hi4 * 8];
                    #pragma unroll
                    for (int mi = 0; mi < 4; ++mi)
                        acc[w][mi][ni] = __builtin_amdgcn_mfma_f32_16x16x32_bf16(
                            af[mi][kk], bfr, acc[w][mi][ni], 0, 0, 0);
                }
        __syncthreads();
    }

    const float* bias[3] = { bq, bk, bv };
    for (int w = 0; w < 3; ++w) {
        #pragma unroll
        for (int mi = 0; mi < 4; ++mi)
            #pragma unroll
            for (int ni = 0; ni < 2; ++ni)
                #pragma unroll
                for (int j = 0; j < 4; ++j) {
                    int r = wm * 64 + mi * 16 + hi4 * 4 + j;
                    int c = wn * 32 + ni * 16 + lo4;
                    float v = acc[w][mi][ni][j] + bias[w][n0 + c];
                    a_lds[r][c] = f2b(fmaxf(v, 0.f));
                }
        __syncthreads();
        if (w == 0) {
            #pragma unroll
            for (int i = 0; i < 4; ++i) {
                int ch = i * 256 + tid;
                int row = ch >> 3, c8 = (ch & 7) * 8;
                *(s16x8*)(qO + (size_t)(s0 + row) * 256 + n0 + c8) = *(s16x8*)&a_lds[row][c8];
            }
        } else if (w == 1) {
            #pragma unroll
            for (int i = 0; i < 4; ++i) {
                int ch = i * 256 + tid;
                int row = ch >> 3, c8 = (ch & 7) * 8;
                int swz = ((c8 >> 3) ^ (row & 7)) * 8;      // seq-keyed chunk XOR
                *(s16x8*)(kO + (size_t)(s0 + row) * 256 + n0 + swz) = *(s16x8*)&a_lds[row][c8];
            }
        } else {
            int bb = s0 >> 10, nn = s0 & 1023;              // block spans a single batch
            #pragma unroll
            for (int i = 0; i < 4; ++i) {
                int ch = i * 256 + tid;
                int h = ch >> 4, sc = (ch & 15) * 8;
                s16x8 t;
                #pragma unroll
                for (int e = 0; e < 8; ++e) t[e] = a_lds[sc + e][h];
                int cil = sc >> 3;                          // 0..15
                int swz = (cil & 8) | ((cil & 7) ^ ((n0 + h) & 7));   // h-keyed chunk XOR
                *(s16x8*)(vtO + ((size_t)bb * 256 + n0 + h) * 1024 + nn + swz * 8) = t;
            }
        }
        __syncthreads();
    }
}

// ---- flash attention: 8 waves/block, Q-tile 128, double-buffered K/V, counted vmcnt ----
// Mask is streamed raw (f32) through the same prefetch pipeline: 16 scalar loads
// per lane per kt, issued one full kt-phase ahead (HBM pipe is otherwise idle).
__global__ __launch_bounds__(512) void attn(
        const short* __restrict__ q, const short* __restrict__ k,
        const short* __restrict__ vt, const float* __restrict__ mask,
        short* __restrict__ attv) {
    __shared__ short kbuf[2][16384];        // 2 x K[64][256] (row-XOR-swizzled layout)
    __shared__ short vbuf[2][16384];        // 2 x V[256][64] (h-XOR-swizzled layout)
    __shared__ short p_lds[8][16][72];      // per-wave P relayout / epilogue bounce
    const int tid = threadIdx.x, wid = tid >> 6, l = tid & 63;
    const int lo4 = l & 15, hi4 = l >> 4;
    const int bid = blockIdx.x;
    const int swz = (bid & 7) * 32 + (bid >> 3);    // XCD-chunked: 4 batches per XCD
    const int b = swz >> 3, qb = swz & 7;
    const int q0 = qb * 128 + wid * 16;
    const size_t bq_row = (size_t)b * 1024 + q0;

    const short* kb  = k  + (size_t)b * 1024 * 256;
    const short* vtg = vt + (size_t)b * 256 * 1024;
    const float* mb  = mask + ((size_t)b * 1024 + q0 + hi4 * 4) * 1024 + lo4;

#define STAGE_K(bufi, c0_) do { const short* sg_ = kb + (size_t)(c0_) * 256;          \
    _Pragma("unroll") for (int i_ = 0; i_ < 4; ++i_) { int cb_ = i_ * 512 + wid * 64; \
        gl_lds16(sg_ + (size_t)(cb_ + l) * 8, &kbuf[bufi][cb_ * 8]); } } while (0)
#define STAGE_V(bufi, c0_) do {                                                       \
    _Pragma("unroll") for (int i_ = 0; i_ < 4; ++i_) { int cb_ = i_ * 512 + wid * 64; \
        int ch_ = cb_ + l; int h_ = ch_ >> 3, cc_ = ch_ & 7;                          \
        gl_lds16(vtg + (size_t)h_ * 1024 + (c0_) + cc_ * 8, &vbuf[bufi][cb_ * 8]); } } while (0)
// 16 f32 loads: dst[j][ct] = mask[q0+hi4*4+j][c0 + ct*16 + lo4]
#define LOAD_MASK(dst, c0_) do {                                                      \
    _Pragma("unroll") for (int j_ = 0; j_ < 4; ++j_) {                                \
        const float* mr_ = mb + (size_t)j_ * 1024 + (c0_);                            \
        dst[j_] = (f32x4){ mr_[0], mr_[16], mr_[32], mr_[48] }; } } while (0)

    s16x8 qf[8];
    {
        const short* qp = q + (bq_row + lo4) * 256 + hi4 * 8;
        #pragma unroll
        for (int t = 0; t < 8; ++t) qf[t] = *(const s16x8*)(qp + t * 32);
    }
    f32x4 oacc[16];
    #pragma unroll
    for (int t = 0; t < 16; ++t) oacc[t] = (f32x4){0.f, 0.f, 0.f, 0.f};
    float m_run[4] = { -1e30f, -1e30f, -1e30f, -1e30f };
    float l_run[4] = { 0.f, 0.f, 0.f, 0.f };
    f32x4 mkc[4], mkn[4];                   // mask dbuf: [j] -> (ct0..ct3)

    // prologue: stage tile 0 (K: 4 loads, mask: 16, V: 4)
    STAGE_K(0, 0);
    LOAD_MASK(mkc, 0);
    STAGE_V(0, 0);

    for (int t = 0; t < 16; ++t) {
        const int cur = t & 1;
        const int c0 = t * 64;
        // ---- issue next K stage + next mask, then wait for K[t] (counted) ----
        if (t < 15) {
            STAGE_K(cur ^ 1, c0 + 64);                      // +4 vmem
            LOAD_MASK(mkn, c0 + 64);                        // +16 vmem
            // younger-than-K[t]: mask[t](16) + V[t](4) + K[t+1](4) + mask[t+1](16) = 40
            asm volatile("s_waitcnt vmcnt(40)" ::: "memory");
        } else {
            // younger-than-K[15]: mask[15](16) + V[15](4) = 20
            asm volatile("s_waitcnt vmcnt(20)" ::: "memory");
        }
        __builtin_amdgcn_s_barrier();
        // ---- QK^T on kbuf[cur] ----
        f32x4 s[4];
        #pragma unroll
        for (int ct = 0; ct < 4; ++ct) s[ct] = (f32x4){0.f, 0.f, 0.f, 0.f};
        __builtin_amdgcn_s_setprio(1);
        #pragma unroll
        for (int ct = 0; ct < 4; ++ct) {
            int row = ct * 16 + lo4, rx = row & 7;
            #pragma unroll
            for (int tt = 0; tt < 8; ++tt) {
                int ch = tt * 4 + hi4;
                int sc = (ch & 24) | ((ch & 7) ^ rx);
                s16x8 kf = *(s16x8*)&kbuf[cur][row * 256 + sc * 8];
                s[ct] = __builtin_amdgcn_mfma_f32_16x16x32_bf16(qf[tt], kf, s[ct], 0, 0, 0);
            }
        }
        __builtin_amdgcn_s_setprio(0);
        // ---- masked online softmax (mask f32 in regs) ----
        float sm[4][4];
        #pragma unroll
        for (int j = 0; j < 4; ++j) {
            sm[0][j] = (mkc[j].x != 0.f) ? s[0][j] : -1e30f;
            sm[1][j] = (mkc[j].y != 0.f) ? s[1][j] : -1e30f;
            sm[2][j] = (mkc[j].z != 0.f) ? s[2][j] : -1e30f;
            sm[3][j] = (mkc[j].w != 0.f) ? s[3][j] : -1e30f;
        }
        float scale[4], p[4][4];
        #pragma unroll
        for (int j = 0; j < 4; ++j) {
            float tmx = fmaxf(fmaxf(sm[0][j], sm[1][j]), fmaxf(sm[2][j], sm[3][j]));
            tmx = fmaxf(tmx, __shfl_xor(tmx, 1));
            tmx = fmaxf(tmx, __shfl_xor(tmx, 2));
            tmx = fmaxf(tmx, __shfl_xor(tmx, 4));
            tmx = fmaxf(tmx, __shfl_xor(tmx, 8));
            float mnew = fmaxf(m_run[j], tmx);
            scale[j] = __expf(m_run[j] - mnew);
            m_run[j] = mnew;
            float su = 0.f;
            #pragma unroll
            for (int ct = 0; ct < 4; ++ct) { p[ct][j] = __expf(sm[ct][j] - mnew); su += p[ct][j]; }
            su += __shfl_xor(su, 1);
            su += __shfl_xor(su, 2);
            su += __shfl_xor(su, 4);
            su += __shfl_xor(su, 8);
            l_run[j] = l_run[j] * scale[j] + su;
        }
        #pragma unroll
        for (int tt = 0; tt < 16; ++tt)
            #pragma unroll
            for (int j = 0; j < 4; ++j) oacc[tt][j] *= scale[j];
        // ---- P (D-layout) -> per-wave LDS -> A-fragment ----
        #pragma unroll
        for (int ct = 0; ct < 4; ++ct)
            #pragma unroll
            for (int j = 0; j < 4; ++j)
                p_lds[wid][hi4 * 4 + j][ct * 16 + lo4] = f2b(p[ct][j]);
        asm volatile("s_waitcnt lgkmcnt(0)" ::: "memory");
        __builtin_amdgcn_sched_barrier(0);
        s16x8 pa0 = *(s16x8*)&p_lds[wid][lo4][hi4 * 8];
        s16x8 pa1 = *(s16x8*)&p_lds[wid][lo4][32 + hi4 * 8];
        // ---- issue next V stage, then wait for V[t] (counted) ----
        if (t < 15) {
            STAGE_V(cur ^ 1, c0 + 64);                      // +4 vmem
            // younger-than-V[t]: K[t+1](4) + mask[t+1](16) + V[t+1](4) = 24
            asm volatile("s_waitcnt vmcnt(24)" ::: "memory");
        } else {
            asm volatile("s_waitcnt vmcnt(0)" ::: "memory");
        }
        __builtin_amdgcn_s_barrier();
        // ---- PV on vbuf[cur] ----
        __builtin_amdgcn_s_setprio(1);
        #pragma unroll
        for (int nt = 0; nt < 16; ++nt) {
            int h = nt * 16 + lo4, hx = h & 7;
            s16x8 vf0 = *(s16x8*)&vbuf[cur][h * 64 + (hi4 ^ hx) * 8];
            s16x8 vf1 = *(s16x8*)&vbuf[cur][h * 64 + ((hi4 + 4) ^ hx) * 8];
            oacc[nt] = __builtin_amdgcn_mfma_f32_16x16x32_bf16(pa0, vf0, oacc[nt], 0, 0, 0);
            oacc[nt] = __builtin_amdgcn_mfma_f32_16x16x32_bf16(pa1, vf1, oacc[nt], 0, 0, 0);
        }
        __builtin_amdgcn_s_setprio(0);
        // ---- rotate mask regs ----
        if (t < 15) {
            #pragma unroll
            for (int i = 0; i < 4; ++i) mkc[i] = mkn[i];
        }
    }
    // ---- epilogue: normalize, bf16, coalesced store via per-wave LDS (4 passes) ----
    float inv[4];
    #pragma unroll
    for (int j = 0; j < 4; ++j) inv[j] = 1.f / l_run[j];
    #pragma unroll
    for (int g = 0; g < 4; ++g) {
        asm volatile("s_waitcnt lgkmcnt(0)" ::: "memory");  // prior pass reads done
        #pragma unroll
        for (int ntl = 0; ntl < 4; ++ntl)
            #pragma unroll
            for (int j = 0; j < 4; ++j)
                p_lds[wid][hi4 * 4 + j][ntl * 16 + lo4] = f2b(oacc[g * 4 + ntl][j] * inv[j]);
        asm volatile("s_waitcnt lgkmcnt(0)" ::: "memory");
        __builtin_amdgcn_sched_barrier(0);
        s16x8 r0 = *(s16x8*)&p_lds[wid][lo4][hi4 * 16];
        s16x8 r1 = *(s16x8*)&p_lds[wid][lo4][hi4 * 16 + 8];
        short* op = attv + (bq_row + lo4) * 256 + g * 64 + hi4 * 16;
        *(s16x8*)op = r0;
        *(s16x8*)(op + 8) = r1;
    }
#undef STAGE_K
#undef STAGE_V
#undef LOAD_MASK
}

// ---- output GEMM: attv bf16 @ Wo^T + bo -> relu -> f32 ----
__global__ __launch_bounds__(256) void out_gemm(
        const short* __restrict__ a, const short* __restrict__ Wto,
        const float* __restrict__ bo, float* __restrict__ out) {
    __shared__ short a_lds[128][72];
    __shared__ short b_lds[64][72];
    __shared__ float bounce[128][68];
    const int tid = threadIdx.x;
    const int bm = blockIdx.x >> 2, bn = blockIdx.x & 3;
    const int s0 = bm * 128, n0 = bn * 64;
    const int wid = tid >> 6, l = tid & 63, lo4 = l & 15, hi4 = l >> 4;
    const int wm = wid >> 1, wn = wid & 1;
    f32x4 acc[4][2];
    #pragma unroll
    for (int mi = 0; mi < 4; ++mi)
        #pragma unroll
        for (int ni = 0; ni < 2; ++ni) acc[mi][ni] = (f32x4){0.f, 0.f, 0.f, 0.f};

    for (int kt = 0; kt < 4; ++kt) {
        const int k0 = kt * 64;
        #pragma unroll
        for (int i = 0; i < 4; ++i) {
            int ch = i * 256 + tid;
            int row = ch >> 3, c8 = (ch & 7) * 8;
            *(s16x8*)&a_lds[row][c8] = *(const s16x8*)(a + (size_t)(s0 + row) * 256 + k0 + c8);
        }
        #pragma unroll
        for (int i = 0; i < 2; ++i) {
            int ch = i * 256 + tid;
            int n = ch >> 3, c8 = (ch & 7) * 8;
            *(s16x8*)&b_lds[n][c8] = *(const s16x8*)(Wto + (size_t)(n0 + n) * 256 + k0 + c8);
        }
        __syncthreads();
        s16x8 af[4][2];
        #pragma unroll
        for (int mi = 0; mi < 4; ++mi)
            #pragma unroll
            for (int kk = 0; kk < 2; ++kk)
                af[mi][kk] = *(s16x8*)&a_lds[wm * 64 + mi * 16 + lo4][kk * 32 + hi4 * 8];
        #pragma unroll
        for (int ni = 0; ni < 2; ++ni)
            #pragma unroll
            for (int kk = 0; kk < 2; ++kk) {
                s16x8 bfr = *(s16x8*)&b_lds[wn * 32 + ni * 16 + lo4][kk * 32 + hi4 * 8];
                #pragma unroll
                for (int mi = 0; mi < 4; ++mi)
                    acc[mi][ni] = __builtin_amdgcn_mfma_f32_16x16x32_bf16(
                        af[mi][kk], bfr, acc[mi][ni], 0, 0, 0);
            }
        __syncthreads();
    }
    #pragma unroll
    for (int mi = 0; mi < 4; ++mi)
        #pragma unroll
        for (int ni = 0; ni < 2; ++ni)
            #pragma unroll
            for (int j = 0; j < 4; ++j) {
                int r = wm * 64 + mi * 16 + hi4 * 4 + j;
                int c = wn * 32 + ni * 16 + lo4;
                bounce[r][c] = fmaxf(acc[mi][ni][j] + bo[n0 + c], 0.f);
            }
    __syncthreads();
    #pragma unroll
    for (int i = 0; i < 8; ++i) {
        int ch = i * 256 + tid;
        int row = ch >> 4, c4 = (ch & 15) * 4;
        *(f32x4*)(out + (size_t)(s0 + row) * 256 + n0 + c4) = *(f32x4*)&bounce[row][c4];
    }
}

extern "C" void kernel_launch(void* const* d_in, const int* in_sizes, int n_in,
                              void* d_out, int out_size, void* d_ws, size_t ws_size,
                              hipStream_t stream) {
    const float* x    = (const float*)d_in[0];
    const float* mask = (const float*)d_in[1];
    const float* Wv   = (const float*)d_in[2];
    const float* bv   = (const float*)d_in[3];
    const float* Wk   = (const float*)d_in[4];
    const float* bk   = (const float*)d_in[5];
    const float* Wq   = (const float*)d_in[6];
    const float* bq   = (const float*)d_in[7];
    const float* Wo   = (const float*)d_in[8];
    const float* bo   = (const float*)d_in[9];
    float* out = (float*)d_out;

    char* ws = (char*)d_ws;
    short*    Wt  = (short*)ws;                               // 512 KB @ 0
    short*    qB  = (short*)(ws + (1 << 20));                 // 16 MB @ 1 MB
    short*    kB  = qB  + (size_t)32768 * 256;                // @ 17 MB
    short*    vtB = kB  + (size_t)32768 * 256;                // @ 33 MB
    short*    avB = vtB + (size_t)32768 * 256;                // @ 49 MB (ends 65 MB)
    (void)in_sizes; (void)n_in; (void)out_size; (void)ws_size;

    prep_w<<<1024, 256, 0, stream>>>(Wq, Wk, Wv, Wo, Wt);
    qkv_gemm<<<1024, 256, 0, stream>>>(x, Wt, bq, bk, bv, qB, kB, vtB);
    attn<<<256, 512, 0, stream>>>(qB, kB, vtB, mask, avB);
    out_gemm<<<1024, 256, 0, stream>>>(avB, Wt + 3 * 65536, bo, out);
}